// Round 13
// baseline (12265.880 us; speedup 1.0000x reference)
//
#include <hip/hip_runtime.h>
#include <hip/hip_fp16.h>

#define B_ 256
#define T_ 512
#define H_ 2048
#define C_ 128
#define ASTR 520        // LDS A row stride (fp16)
#define POLLCAP 50000   // every cross-WG wait bounded: bug -> fast absmax-fail, never timeout

// ws byte offsets
#define WS_H0 (0u)
#define WS_H1 (1u << 20)
#define WS_BT (2u << 20)   // 8 MB fp16 BT[n][s] (W_hh^T, sigma-permuted K)

typedef _Float16 half8 __attribute__((ext_vector_type(8)));
typedef float floatx4 __attribute__((ext_vector_type(4)));

__device__ unsigned g_cnt[8 * T_];   // per-(xcd,t) arrival counters
__device__ unsigned g_census[16];    // [0..8) per-XCD WG census; [8] rendezvous count
__device__ unsigned g_gcount[16];    // [0] global flush counter (own line)

// h storage K-permuted (r7-proven): within each 32-col block, storage 2j<-col j, 2j+1<-col j+16.
//   sigma(s)   = (s&~31) + ((s&31)>>1) + ((s&1)<<4)

// IF$-coherent loads (sc0 sc1): read the device coherence point (r6/r7-proven fresh).
__device__ __forceinline__ half8 llc_load16(const _Float16* p) {
    union { unsigned long long u[2]; half8 h; } v;
    const unsigned long long* q = (const unsigned long long*)p;
    v.u[0] = __hip_atomic_load(q,     __ATOMIC_RELAXED, __HIP_MEMORY_SCOPE_AGENT);
    v.u[1] = __hip_atomic_load(q + 1, __ATOMIC_RELAXED, __HIP_MEMORY_SCOPE_AGENT);
    return v.h;
}

__device__ __forceinline__ int xcc_id() {
    int x;
    asm volatile("s_getreg_b32 %0, hwreg(HW_REG_XCC_ID)" : "=s"(x));
    return x & 7;
}

// ---- one-time: BT[n][s] = (fp16) W_hh[sigma(s)][n] (read-only; L2-cacheable) ----
__global__ void convert_whh(const float* __restrict__ W, _Float16* __restrict__ BT) {
    __shared__ float tile[64][65];
    const int kb = blockIdx.x * 64, nb = blockIdx.y * 64;
    const int tid = threadIdx.x;
    const int rc = tid & 63, rr = tid >> 6;
#pragma unroll
    for (int i = 0; i < 16; ++i)
        tile[i * 4 + rr][rc] = W[(size_t)(kb + i * 4 + rr) * H_ + nb + rc];
    __syncthreads();
    const int j = tid & 15, blk = (tid >> 4) & 1, nof = tid >> 5;
#pragma unroll
    for (int i = 0; i < 8; ++i) {
        int n = i * 8 + nof;
        _Float16 v0 = (_Float16)tile[blk * 32 + j][n];
        _Float16 v1 = (_Float16)tile[blk * 32 + 16 + j][n];
        unsigned pk = ((unsigned)__builtin_bit_cast(unsigned short, v1) << 16)
                    |  (unsigned)__builtin_bit_cast(unsigned short, v0);
        *(unsigned*)(BT + (size_t)(nb + n) * H_ + kb + blk * 32 + 2 * j) = pk;
    }
}

// ---- h0 (permuted) = tanh(W_hx[x[:,0]] + b_h); zero all sync state ----
__global__ void init_h(const int* __restrict__ x, const float* __restrict__ W_hx,
                       const float* __restrict__ b_h, char* __restrict__ ws) {
    int idx = blockIdx.x * blockDim.x + threadIdx.x;
    if (idx < 8 * T_) g_cnt[idx] = 0;
    if (idx < 16) { g_census[idx] = 0; g_gcount[idx] = 0; }
    _Float16* h0 = (_Float16*)(ws + WS_H0);
    int b = idx >> 11, s = idx & (H_ - 1);
    int j = (s & ~31) + ((s & 31) >> 1) + ((s & 1) << 4);
    int xv = x[b * T_];
    h0[idx] = (_Float16)tanhf(W_hx[(size_t)xv * H_ + j] + b_h[j]);
}

#define STAGE_LOAD(hb, qq, r) {                                             \
    const _Float16* sp = (hb) + (size_t)(rbr + srow) * H_ + (qq) * 512 + skb; \
    r[0] = llc_load16(sp);      r[1] = llc_load16(sp + 8);                  \
    r[2] = llc_load16(sp + 16); r[3] = llc_load16(sp + 24); }

#define STAGE_WRITE(buf, r) {                                               \
    _Float16* dp = &As[buf][srow][skb];                                     \
    *(half8*)(dp)      = r[0]; *(half8*)(dp + 8)  = r[1];                   \
    *(half8*)(dp + 16) = r[2]; *(half8*)(dp + 24) = r[3]; }

#define COMPUTE(qq) {                                                       \
    const _Float16* ar  = &As[(qq) & 1][l15][kl];                           \
    const _Float16* b0p = BT + (size_t)(cw + l15) * H_ + (qq) * 512 + kl;   \
    const _Float16* b1p = BT + (size_t)(cw + 16 + l15) * H_ + (qq) * 512 + kl; \
    _Pragma("unroll")                                                       \
    for (int i = 0; i < 16; ++i) {                                          \
        half8 a  = *(const half8*)(ar  + i * 32);                           \
        half8 b0 = *(const half8*)(b0p + i * 32);                           \
        half8 b1 = *(const half8*)(b1p + i * 32);                           \
        acc0 = __builtin_amdgcn_mfma_f32_16x16x32_f16(a, b0, acc0, 0, 0, 0);\
        acc1 = __builtin_amdgcn_mfma_f32_16x16x32_f16(a, b1, acc1, 0, 0, 0);\
    } }

// ---- recurrence: 256 WGs (1/CU) x 256 thr; WG tile 16(M) x 128(N) ----
// Publish: NORMAL u32 stores (dirty local L2) + ONE buffer_wbl2 per XCD per step,
// executed by the LAST arriver on that XCD (census-counted via HW XCC_ID). Consumers
// gate on a single monotonic gcount (= #XCD-flushes); h reads via sc0sc1 (IF$-fresh).
// Atomic ops/step drop 262144 -> ~300; wbl2/step 256 -> 8 (parallel across TCCs).
__global__ __launch_bounds__(256, 1)
void rnn_steps(char* __restrict__ ws, const int* __restrict__ x,
               const float* __restrict__ W_hx, const float* __restrict__ b_h) {
    __shared__ _Float16 As[2][16][ASTR];   // 33.3 KB
    __shared__ unsigned s_cen;
    __shared__ int s_ne;
    _Float16* h0 = (_Float16*)(ws + WS_H0);
    _Float16* h1 = (_Float16*)(ws + WS_H1);
    const _Float16* BT = (const _Float16*)(ws + WS_BT);

    const int bid = blockIdx.x;
    const int rb  = bid >> 4;          // rowblock 0..15 (16 batch rows)
    const int cb  = bid & 15;          // colblock 0..15 (128 cols)
    const int nb  = cb * 128;
    const int tid = threadIdx.x;
    const int myxcd = xcc_id();

    // census rendezvous (once): count WGs per physical XCD; all WGs learn the counts
    if (tid == 0) {
        __hip_atomic_fetch_add(&g_census[myxcd], 1u, __ATOMIC_RELAXED, __HIP_MEMORY_SCOPE_AGENT);
        __hip_atomic_fetch_add(&g_census[8],     1u, __ATOMIC_RELAXED, __HIP_MEMORY_SCOPE_AGENT);
        int p = 0;
        while (__hip_atomic_load(&g_census[8], __ATOMIC_RELAXED, __HIP_MEMORY_SCOPE_AGENT) < 256u
               && p < POLLCAP) { __builtin_amdgcn_s_sleep(2); ++p; }
        int ne = 0; unsigned cen = 1;
        for (int i = 0; i < 8; ++i) {
            unsigned c = __hip_atomic_load(&g_census[i], __ATOMIC_RELAXED, __HIP_MEMORY_SCOPE_AGENT);
            if (c > 0) ++ne;
            if (i == myxcd) cen = c;
        }
        s_ne = ne; s_cen = cen;
    }
    __syncthreads();
    const unsigned nonempty = (unsigned)s_ne;
    const unsigned mycen    = s_cen;

    const int w   = tid >> 6;
    const int l   = tid & 63;
    const int l15 = l & 15;
    const int q4  = l >> 4;
    const int kl  = q4 << 3;
    const int cw  = nb + w * 32;
    const int rbr = rb * 16;
    const int srow = tid >> 4;
    const int skb  = (tid & 15) * 32;
    const int r0 = rbr + q4 * 4;
    const int c0 = cw + l15;
    const float bh0 = b_h[c0], bh1 = b_h[c0 + 16];

    for (int t = 1; t < T_; ++t) {
        const _Float16* __restrict__ hc = (t & 1) ? h0 : h1;  // h(t-1)
        _Float16* __restrict__ hn       = (t & 1) ? h1 : h0;  // h(t)

        // gate: all XCDs flushed step t-1 (monotonic gcount; induction-safe)
        if (tid == 0) {
            const unsigned needg = nonempty * (unsigned)(t - 1);
            int p = 0;
            while (__hip_atomic_load(&g_gcount[0], __ATOMIC_RELAXED, __HIP_MEMORY_SCOPE_AGENT)
                       < needg && p < POLLCAP) { __builtin_amdgcn_s_sleep(2); ++p; }
        }
        __syncthreads();

        // epilogue-gather prefetch (warm L1/L2)
        int   xv[4];
        float wx0[4], wx1[4];
#pragma unroll
        for (int jj = 0; jj < 4; ++jj) xv[jj] = x[(r0 + jj) * T_ + t];
#pragma unroll
        for (int jj = 0; jj < 4; ++jj) {
            wx0[jj] = W_hx[(size_t)xv[jj] * H_ + c0];
            wx1[jj] = W_hx[(size_t)xv[jj] * H_ + c0 + 16];
        }

        floatx4 acc0 = {0.f, 0.f, 0.f, 0.f}, acc1 = {0.f, 0.f, 0.f, 0.f};

        // A-tile via LDS, 2-chunk pipeline (r12-proven); A reads sc0sc1 (IF$-fresh)
        {
            half8 rA[4];
            STAGE_LOAD(hc, 0, rA);
            STAGE_WRITE(0, rA);
        }
        __syncthreads();
#pragma unroll
        for (int q = 0; q < 4; ++q) {
            half8 rN[4];
            if (q < 3) STAGE_LOAD(hc, q + 1, rN);   // IF$ latency hides under COMPUTE(q)
            COMPUTE(q);
            if (q < 3) {
                __syncthreads();
                STAGE_WRITE((q + 1) & 1, rN);
                __syncthreads();
            }
        }

        // publish h(t): PLAIN u32 stores -> dirty local L2 (flushed by this XCD's leader)
#pragma unroll
        for (int jj = 0; jj < 4; ++jj) {
            float z0 = acc0[jj] + wx0[jj] + bh0;
            float z1 = acc1[jj] + wx1[jj] + bh1;
            _Float16 p0 = (_Float16)tanhf(z0), p1 = (_Float16)tanhf(z1);
            unsigned pv = ((unsigned)__builtin_bit_cast(unsigned short, p1) << 16)
                        |  (unsigned)__builtin_bit_cast(unsigned short, p0);
            *(unsigned*)(hn + (size_t)(r0 + jj) * H_ + cw + 2 * l15) = pv;
        }

        // arrive; LAST arriver on this XCD flushes its L2 (waitcnt + buffer_wbl2 sc1)
        __syncthreads();   // vmcnt drain: all 4 waves' stores acked at local L2
        if (tid == 0) {
            unsigned prev = __hip_atomic_fetch_add(&g_cnt[myxcd * T_ + t], 1u,
                                                   __ATOMIC_RELAXED, __HIP_MEMORY_SCOPE_AGENT);
            if (prev == mycen - 1) {   // leader: co-XCD stores all in this L2 (their RMWs done)
                __builtin_amdgcn_fence(__ATOMIC_RELEASE, "agent");   // r4-proven publish
                __hip_atomic_fetch_add(&g_gcount[0], 1u,
                                       __ATOMIC_RELAXED, __HIP_MEMORY_SCOPE_AGENT);
            }
        }
        // no wait — next step's gate polls gcount
    }
}

// ---- out[b,c] = h[b,:] @ W_ph + b_p (fp32); h in permuted storage order ----
__global__ void final_proj(const char* __restrict__ ws, const float* __restrict__ W_ph,
                           const float* __restrict__ b_p, float* __restrict__ out) {
    __shared__ float part[C_];
    const _Float16* h = (const _Float16*)(ws + WS_H1);   // h after t=511 (odd)
    const int b  = blockIdx.x;
    const int c  = threadIdx.x & (C_ - 1);
    const int hh = threadIdx.x >> 7;
    const int j0 = hh * (H_ / 2);
    float acc = 0.f;
#pragma unroll 4
    for (int s = j0; s < j0 + H_ / 2; ++s) {
        int k = (s & ~31) + ((s & 31) >> 1) + ((s & 1) << 4);   // sigma(s)
        acc = fmaf((float)h[(size_t)b * H_ + s], W_ph[k * C_ + c], acc);
    }
    if (hh) part[c] = acc;
    __syncthreads();
    if (!hh) out[b * C_ + c] = acc + part[c] + b_p[c];
}

extern "C" void kernel_launch(void* const* d_in, const int* in_sizes, int n_in,
                              void* d_out, int out_size, void* d_ws, size_t ws_size,
                              hipStream_t stream) {
    const int*   x    = (const int*)d_in[0];
    const float* W_hx = (const float*)d_in[1];
    const float* W_hh = (const float*)d_in[2];
    const float* W_ph = (const float*)d_in[3];
    const float* b_h  = (const float*)d_in[4];
    const float* b_p  = (const float*)d_in[5];
    float* out = (float*)d_out;
    char* ws = (char*)d_ws;

    convert_whh<<<dim3(H_ / 64, H_ / 64), 256, 0, stream>>>(W_hh, (_Float16*)(ws + WS_BT));
    init_h<<<(B_ * H_) / 256, 256, 0, stream>>>(x, W_hx, b_h, ws);

    char* pws = ws;
    const int* px = x; const float* pwhx = W_hx; const float* pbh = b_h;
    void* args[] = {(void*)&pws, (void*)&px, (void*)&pwhx, (void*)&pbh};
    hipError_t e = hipLaunchCooperativeKernel((void*)rnn_steps, dim3(256), dim3(256),
                                              args, 0, stream);
    if (e != hipSuccess) {
        rnn_steps<<<dim3(256), dim3(256), 0, stream>>>(pws, px, pwhx, pbh);
    }

    final_proj<<<B_, 256, 0, stream>>>(ws, W_ph, b_p, out);
}

// Round 17
// 9639.467 us; speedup vs baseline: 1.2725x; 1.2725x over previous
//
#include <hip/hip_runtime.h>
#include <hip/hip_fp16.h>

#define B_ 256
#define T_ 512
#define H_ 2048
#define C_ 128
#define ASTR 520        // fallback LDS A stride (r12-proven)
#define BSTR2 1030      // fast-path LDS B stride (1024 used): ~2-way max bank aliasing (free)
#define POLLCAP 200000  // every cross-WG wait bounded -> bug = fast absmax-fail, never timeout

// ws byte offsets (10 MB, r12-proven capacity)
#define WS_H0 (0u)
#define WS_H1 (1u << 20)
#define WS_BT (2u << 20)   // 8 MB fp16 BT[n][s] (W_hh^T, sigma-permuted K)

typedef _Float16 half8 __attribute__((ext_vector_type(8)));
typedef float floatx4 __attribute__((ext_vector_type(4)));

// sync: [0..15] census; scnt[xcd]=g_sync[32+xcd*32]; fallback flags at g_sync+4384.
__device__ unsigned g_sync[8192];
__device__ _Float16 g_fb[2][8][32][H_];      // per-XCD h double buffer (XCD-local L2 resident)

// sigma (r7-proven): within each 32-col block, storage 2j<-col j, 2j+1<-col j+16.
//   sigma(s) = (s&~31) + ((s&31)>>1) + ((s&1)<<4)

// IF$-coherent load (sc0 sc1) — fallback path (r7-proven).
__device__ __forceinline__ half8 llc_load16(const _Float16* p) {
    union { unsigned long long u[2]; half8 h; } v;
    const unsigned long long* q = (const unsigned long long*)p;
    v.u[0] = __hip_atomic_load(q,     __ATOMIC_RELAXED, __HIP_MEMORY_SCOPE_AGENT);
    v.u[1] = __hip_atomic_load(q + 1, __ATOMIC_RELAXED, __HIP_MEMORY_SCOPE_AGENT);
    return v.h;
}

__device__ __forceinline__ int xcc_id() {
    int x;
    asm volatile("s_getreg_b32 %0, hwreg(HW_REG_XCC_ID)" : "=s"(x));
    return x & 7;
}

// flags: AGENT-scope atomics (r7/r10/r11/r12-proven). ~32 RMW + 32 polls per XCD per step.
__device__ __forceinline__ void flag_inc(unsigned* p) {
    __hip_atomic_fetch_add(p, 1u, __ATOMIC_RELAXED, __HIP_MEMORY_SCOPE_AGENT);
}
__device__ __forceinline__ void flag_poll_ge(const unsigned* p, unsigned tgt) {
    int n = 0;
    while (__hip_atomic_load(p, __ATOMIC_RELAXED, __HIP_MEMORY_SCOPE_AGENT) < tgt
           && n < POLLCAP) { __builtin_amdgcn_s_sleep(2); ++n; }
}

// ---- one-time: BT[n][s] = (fp16) W_hh[sigma(s)][n] ----
__global__ void convert_whh(const float* __restrict__ W, _Float16* __restrict__ BT) {
    __shared__ float tile[64][65];
    const int kb = blockIdx.x * 64, nb = blockIdx.y * 64;
    const int tid = threadIdx.x;
    const int rc = tid & 63, rr = tid >> 6;
#pragma unroll
    for (int i = 0; i < 16; ++i)
        tile[i * 4 + rr][rc] = W[(size_t)(kb + i * 4 + rr) * H_ + nb + rc];
    __syncthreads();
    const int j = tid & 15, blk = (tid >> 4) & 1, nof = tid >> 5;
#pragma unroll
    for (int i = 0; i < 8; ++i) {
        int n = i * 8 + nof;
        _Float16 v0 = (_Float16)tile[blk * 32 + j][n];
        _Float16 v1 = (_Float16)tile[blk * 32 + 16 + j][n];
        unsigned pk = ((unsigned)__builtin_bit_cast(unsigned short, v1) << 16)
                    |  (unsigned)__builtin_bit_cast(unsigned short, v0);
        *(unsigned*)(BT + (size_t)(nb + n) * H_ + kb + blk * 32 + 2 * j) = pk;
    }
}

// ---- h0 (permuted) = tanh(W_hx[x[:,0]] + b_h); zero all sync state ----
__global__ void init_h(const int* __restrict__ x, const float* __restrict__ W_hx,
                       const float* __restrict__ b_h, char* __restrict__ ws) {
    int idx = blockIdx.x * blockDim.x + threadIdx.x;
    if (idx < 8192) g_sync[idx] = 0;
    _Float16* h0 = (_Float16*)(ws + WS_H0);
    int b = idx >> 11, s = idx & (H_ - 1);
    int j = (s & ~31) + ((s & 31) >> 1) + ((s & 1) << 4);
    int xv = x[b * T_];
    h0[idx] = (_Float16)tanhf(W_hx[(size_t)xv * H_ + j] + b_h[j]);
}

// sc0 loads (L1-bypass, local-L2-hit) — r10-proven instrument
#define AL(dst, blk) { const _Float16* _ab = ap + (blk) * 256;              \
    _Pragma("unroll") for (int u = 0; u < 8; ++u)                           \
        asm volatile("global_load_dwordx4 %0, %1, off offset:%2 sc0"        \
                     : "=v"(dst[u]) : "v"(_ab), "i"(u * 64)); }

// loop2: 128-fp16 block = 4 A + 4 B0 + 4 B1 sc0 loads (12, in this issue order)
#define AL2(Aa, Bb0, Bb1, q) {                                              \
    const _Float16* _a2 = ap2 + (q) * 128;                                  \
    const _Float16* _b0 = btp0 + (q) * 128;                                 \
    const _Float16* _b1 = btp1 + (q) * 128;                                 \
    _Pragma("unroll") for (int u = 0; u < 4; ++u)                           \
        asm volatile("global_load_dwordx4 %0, %1, off offset:%2 sc0"        \
                     : "=v"(Aa[u]) : "v"(_a2), "i"(u * 64));                \
    _Pragma("unroll") for (int u = 0; u < 4; ++u)                           \
        asm volatile("global_load_dwordx4 %0, %1, off offset:%2 sc0"        \
                     : "=v"(Bb0[u]) : "v"(_b0), "i"(u * 64));               \
    _Pragma("unroll") for (int u = 0; u < 4; ++u)                           \
        asm volatile("global_load_dwordx4 %0, %1, off offset:%2 sc0"        \
                     : "=v"(Bb1[u]) : "v"(_b1), "i"(u * 64)); }

#define VWAIT(n)                                                            \
    asm volatile("s_waitcnt vmcnt(" #n ")" ::: "memory");                   \
    __builtin_amdgcn_sched_barrier(0);

// fast path compute: B from LDS (loop1)
#define FC_LDS(src, blk)                                                    \
    _Pragma("unroll") for (int u = 0; u < 8; ++u) {                         \
        half8 b0v = *(const half8*)(bsp0 + ((blk) * 8 + u) * 32);           \
        half8 b1v = *(const half8*)(bsp1 + ((blk) * 8 + u) * 32);           \
        acc0 = __builtin_amdgcn_mfma_f32_16x16x32_f16(src[u], b0v, acc0, 0, 0, 0); \
        acc1 = __builtin_amdgcn_mfma_f32_16x16x32_f16(src[u], b1v, acc1, 0, 0, 0); \
    }

// fast path compute: B from registers (loop2)
#define FC_REG(Aa, Bb0, Bb1)                                                \
    _Pragma("unroll") for (int u = 0; u < 4; ++u) {                         \
        acc0 = __builtin_amdgcn_mfma_f32_16x16x32_f16(Aa[u], Bb0[u], acc0, 0, 0, 0); \
        acc1 = __builtin_amdgcn_mfma_f32_16x16x32_f16(Aa[u], Bb1[u], acc1, 0, 0, 0); \
    }

// fallback (r12-proven) pieces
#define POLLF(qq) {                                                         \
    int guard = 0;                                                          \
    for (;;) {                                                              \
        unsigned fvv = need;                                                \
        if (l < 4) fvv = __hip_atomic_load(&gflags[(rb * 16 + (qq) * 4 + l) * 4], \
                                           __ATOMIC_RELAXED, __HIP_MEMORY_SCOPE_AGENT); \
        if (__ballot(fvv >= need) == ~0ull) break;                          \
        if (++guard > POLLCAP) break;                                       \
        __builtin_amdgcn_s_sleep(2);                                        \
    } }

#define STAGE_LOAD(hb, qq, r) {                                             \
    const _Float16* sp = (hb) + (size_t)(rbr + srow) * H_ + (qq) * 512 + skb; \
    r[0] = llc_load16(sp);      r[1] = llc_load16(sp + 8);                  \
    r[2] = llc_load16(sp + 16); r[3] = llc_load16(sp + 24); }

#define STAGE_WRITE(buf, r) {                                               \
    _Float16* dp = Asl + (buf) * 16 * ASTR + srow * ASTR + skb;             \
    *(half8*)(dp)      = r[0]; *(half8*)(dp + 8)  = r[1];                   \
    *(half8*)(dp + 16) = r[2]; *(half8*)(dp + 24) = r[3]; }

#define COMPUTE(qq) {                                                       \
    const _Float16* ar  = Asl + ((qq) & 1) * 16 * ASTR + l15 * ASTR + kl;   \
    const _Float16* b0p = BT + (size_t)(cw + l15) * H_ + (qq) * 512 + kl;   \
    const _Float16* b1p = BT + (size_t)(cw + 16 + l15) * H_ + (qq) * 512 + kl; \
    _Pragma("unroll")                                                       \
    for (int i = 0; i < 16; ++i) {                                          \
        half8 a  = *(const half8*)(ar  + i * 32);                           \
        half8 b0 = *(const half8*)(b0p + i * 32);                           \
        half8 b1 = *(const half8*)(b1p + i * 32);                           \
        acc0 = __builtin_amdgcn_mfma_f32_16x16x32_f16(a, b0, acc0, 0, 0, 0);\
        acc1 = __builtin_amdgcn_mfma_f32_16x16x32_f16(a, b1, acc1, 0, 0, 0);\
    } }

// ---- recurrence: 256 WGs (1/CU) x 256 thr ----
// FAST (census: exactly 32 WGs per XCD — held in r15/r16): XCD k owns batch rows
// [32k,32k+32); WG ns (arrival rank 0..31) owns cols [64ns,64ns+64), FULL K=2048
// (coverage: 32 x 64 = 2048 ✓ — r14-r16's 16x64=1024 bug fixed). h lives in the XCD's
// L2 (plain stores + sc0 loads); B = LDS K-half + streamed K-half from BT (sc0, warm);
// sync = ONE gate + ONE bump per WG per step (agent atomics). FALLBACK: r12 verbatim.
__global__ __launch_bounds__(256, 1)
void rnn_steps(char* __restrict__ ws, const int* __restrict__ x,
               const float* __restrict__ W_hx, const float* __restrict__ b_h) {
    extern __shared__ _Float16 lds[];
    __shared__ int s_fast, s_wslot;
    _Float16* h0 = (_Float16*)(ws + WS_H0);
    _Float16* h1 = (_Float16*)(ws + WS_H1);
    const _Float16* BT = (const _Float16*)(ws + WS_BT);
    unsigned* census = g_sync;
    unsigned* gflags = g_sync + 4384;

    const int bid = blockIdx.x;
    const int tid = threadIdx.x;
    const int myxcd = xcc_id();

    // census rendezvous (agent scope): wslot = arrival rank on this physical XCD
    if (tid == 0) {
        unsigned prev = __hip_atomic_fetch_add(&census[myxcd], 1u, __ATOMIC_RELAXED,
                                               __HIP_MEMORY_SCOPE_AGENT);
        __hip_atomic_fetch_add(&census[8], 1u, __ATOMIC_RELAXED, __HIP_MEMORY_SCOPE_AGENT);
        int p = 0;
        while (__hip_atomic_load(&census[8], __ATOMIC_RELAXED, __HIP_MEMORY_SCOPE_AGENT)
                   < 256u && p < POLLCAP) { __builtin_amdgcn_s_sleep(2); ++p; }
        int ok = (p < POLLCAP);
        if (ok)
            for (int i = 0; i < 8; ++i)
                if (__hip_atomic_load(&census[i], __ATOMIC_RELAXED, __HIP_MEMORY_SCOPE_AGENT)
                        != 32u) { ok = 0; break; }
        s_fast = ok; s_wslot = (int)prev;
    }
    __syncthreads();
    const bool fast = (s_fast != 0);
    const int wslot = s_wslot;

    const int w   = tid >> 6;
    const int l   = tid & 63;
    const int l15 = l & 15;
    const int kl  = (l >> 4) << 3;

    if (fast) {
        const int ns = wslot;              // 0..31: cols [64ns, 64ns+64), full K
        _Float16* bsf = lds;               // [64 cols][BSTR2] holding K 0..1024
        unsigned* scnt = &g_sync[32 + myxcd * 32];

        // LDS fill: B slice, K-lower-half (coalesced from BT)
        {
            const int c = tid >> 2, kseg = (tid & 3) * 256;
            const _Float16* src = BT + (size_t)(ns * 64 + c) * H_ + kseg;
            _Float16* dst = bsf + c * BSTR2 + kseg;
#pragma unroll
            for (int i = 0; i < 32; ++i)
                *(half8*)(dst + i * 8) = *(const half8*)(src + i * 8);
        }
        // prologue: WG ns copies local row ns of h0 into fb[0] (256 thr x 8 fp16 = 2048)
        {
            const _Float16* src = h0 + (size_t)(32 * myxcd + ns) * H_ + tid * 8;
            *(half8*)(&g_fb[0][myxcd][ns][tid * 8]) = *(const half8*)(src);
        }
        __syncthreads();                   // LDS fill + copy stores drained
        if (tid == 0) flag_inc(scnt);      // prologue arrival (32 total)

        const int mrow = 16 * (w & 1);     // wave's local M-half
        const int cblk = 32 * (w >> 1);    // wave's 32-col block within the 64
        const int arow = mrow + l15;
        const int r0l  = mrow + ((l >> 4) << 2);
        const int c0   = 64 * ns + cblk + l15;              // original col
        const float bh0 = b_h[c0], bh1 = b_h[c0 + 16];
        const _Float16* bsp0 = bsf + (cblk + l15) * BSTR2 + kl;
        const _Float16* bsp1 = bsf + (cblk + 16 + l15) * BSTR2 + kl;
        const _Float16* btp0 = BT + (size_t)c0 * H_ + 1024 + kl;        // streamed half
        const _Float16* btp1 = BT + (size_t)(c0 + 16) * H_ + 1024 + kl;
        const unsigned uofs = (unsigned)(64 * ns + cblk) / 2 + (unsigned)l15;

        for (int t = 1; t < T_; ++t) {
            // gate: all 32 cohort WGs completed step t-1 (data ready + WAR-safe)
            if (tid == 0) flag_poll_ge(scnt, 32u * (unsigned)t);
            __syncthreads();

            // epilogue gathers (normal cached; warm)
            int   xv[4];
            float wx0[4], wx1[4];
#pragma unroll
            for (int jj = 0; jj < 4; ++jj)
                xv[jj] = x[(32 * myxcd + r0l + jj) * T_ + t];
#pragma unroll
            for (int jj = 0; jj < 4; ++jj) {
                wx0[jj] = W_hx[(size_t)xv[jj] * H_ + c0];
                wx1[jj] = W_hx[(size_t)xv[jj] * H_ + c0 + 16];
            }
            asm volatile("" ::: "memory");

            const _Float16* ap  = &g_fb[(t - 1) & 1][myxcd][arow][kl];
            const _Float16* ap2 = ap + 1024;
            floatx4 acc0 = {0.f, 0.f, 0.f, 0.f}, acc1 = {0.f, 0.f, 0.f, 0.f};

            // loop1: K 0..1024, A sc0 pipeline, B from LDS
            half8 aA[8], aB[8];
            AL(aA, 0); AL(aB, 1);
            VWAIT(8);  FC_LDS(aA, 0);
            AL(aA, 2); VWAIT(8); FC_LDS(aB, 1);
            AL(aB, 3); VWAIT(8); FC_LDS(aA, 2);
            // loop2 transition: K 1024..2048, 8 blocks of 128, A+B sc0 (12 loads/blk)
            half8 a2A[4], b0A[4], b1A[4], a2B[4], b0B[4], b1B[4];
            AL2(a2A, b0A, b1A, 0);
            VWAIT(12); FC_LDS(aB, 3);      // 12 left = loop2 blk0; aB (older) complete
            AL2(a2B, b0B, b1B, 1); VWAIT(12); FC_REG(a2A, b0A, b1A);
            AL2(a2A, b0A, b1A, 2); VWAIT(12); FC_REG(a2B, b0B, b1B);
            AL2(a2B, b0B, b1B, 3); VWAIT(12); FC_REG(a2A, b0A, b1A);
            AL2(a2A, b0A, b1A, 4); VWAIT(12); FC_REG(a2B, b0B, b1B);
            AL2(a2B, b0B, b1B, 5); VWAIT(12); FC_REG(a2A, b0A, b1A);
            AL2(a2A, b0A, b1A, 6); VWAIT(12); FC_REG(a2B, b0B, b1B);
            AL2(a2B, b0B, b1B, 7); VWAIT(12); FC_REG(a2A, b0A, b1A);
            VWAIT(0);  FC_REG(a2B, b0B, b1B);

            // publish h(t): plain packed u32 stores -> dirty LOCAL L2 (sc0 readers hit it)
            _Float16* fbn = &g_fb[t & 1][myxcd][0][0];
#pragma unroll
            for (int jj = 0; jj < 4; ++jj) {
                float z0 = acc0[jj] + wx0[jj] + bh0;
                float z1 = acc1[jj] + wx1[jj] + bh1;
                _Float16 p0 = (_Float16)tanhf(z0), p1 = (_Float16)tanhf(z1);
                unsigned pv = ((unsigned)__builtin_bit_cast(unsigned short, p1) << 16)
                            |  (unsigned)__builtin_bit_cast(unsigned short, p0);
                ((unsigned*)(fbn + (size_t)(r0l + jj) * H_))[uofs] = pv;
                if (t == T_ - 1)
                    ((unsigned*)(h1 + (size_t)(32 * myxcd + r0l + jj) * H_))[uofs] = pv;
            }
            __syncthreads();               // vmcnt drain: stores acked at local L2
            if (tid == 0) flag_inc(scnt);  // arrive step t
        }
        return;
    }

    // ---------------- FALLBACK: r12-proven IF$ path (verbatim) ----------------
    _Float16* Asl = lds;                   // [2][16][ASTR]
    const int rb  = bid >> 4;
    const int cb  = bid & 15;
    const int nb  = cb * 128;
    const int cw  = nb + w * 32;
    const int rbr = rb * 16;
    const int srow = tid >> 4;
    const int skb  = (tid & 15) * 32;
    const int r0 = rbr + ((l >> 4) << 2);
    const int c0 = cw + l15;
    const float bh0 = b_h[c0], bh1 = b_h[c0 + 16];
    unsigned* myflag = &gflags[(rb * 16 + cb) * 4];

    for (int t = 1; t < T_; ++t) {
        const _Float16* __restrict__ hc = (t & 1) ? h0 : h1;
        _Float16* __restrict__ hn       = (t & 1) ? h1 : h0;
        const unsigned need = (unsigned)(t - 1);

        int   xv[4];
        float wx0[4], wx1[4];
#pragma unroll
        for (int jj = 0; jj < 4; ++jj) xv[jj] = x[(r0 + jj) * T_ + t];
#pragma unroll
        for (int jj = 0; jj < 4; ++jj) {
            wx0[jj] = W_hx[(size_t)xv[jj] * H_ + c0];
            wx1[jj] = W_hx[(size_t)xv[jj] * H_ + c0 + 16];
        }

        floatx4 acc0 = {0.f, 0.f, 0.f, 0.f}, acc1 = {0.f, 0.f, 0.f, 0.f};
        POLLF(0);
        {
            half8 rA[4];
            STAGE_LOAD(hc, 0, rA);
            STAGE_WRITE(0, rA);
        }
        __syncthreads();
#pragma unroll
        for (int q = 0; q < 4; ++q) {
            half8 rN[4];
            if (q < 3) { POLLF(q + 1); STAGE_LOAD(hc, q + 1, rN); }
            COMPUTE(q);
            if (q < 3) {
                __syncthreads();
                STAGE_WRITE((q + 1) & 1, rN);
                __syncthreads();
            }
        }
        unsigned o[4];
#pragma unroll
        for (int jj = 0; jj < 4; ++jj) {
            float z0 = acc0[jj] + wx0[jj] + bh0;
            float z1 = acc1[jj] + wx1[jj] + bh1;
            _Float16 p0 = (_Float16)tanhf(z0), p1 = (_Float16)tanhf(z1);
            unsigned pv = ((unsigned)__builtin_bit_cast(unsigned short, p1) << 16)
                        |  (unsigned)__builtin_bit_cast(unsigned short, p0);
            unsigned* dstp = (unsigned*)(hn + (size_t)(r0 + jj) * H_ + cw + 2 * l15);
            o[jj] = __hip_atomic_exchange(dstp, pv, __ATOMIC_RELAXED,
                                          __HIP_MEMORY_SCOPE_AGENT);
        }
        asm volatile("" :: "v"(o[0]), "v"(o[1]), "v"(o[2]), "v"(o[3]));
        __syncthreads();
        if (tid == 0) {
            __builtin_amdgcn_fence(__ATOMIC_RELEASE, "workgroup");
            __hip_atomic_fetch_add(myflag, 1u, __ATOMIC_RELAXED, __HIP_MEMORY_SCOPE_AGENT);
        }
    }
}

// ---- out[b,c] = h[b,:] @ W_ph + b_p (fp32); h in permuted storage order ----
__global__ void final_proj(const char* __restrict__ ws, const float* __restrict__ W_ph,
                           const float* __restrict__ b_p, float* __restrict__ out) {
    __shared__ float part[C_];
    const _Float16* h = (const _Float16*)(ws + WS_H1);   // h after t=511 (odd)
    const int b  = blockIdx.x;
    const int c  = threadIdx.x & (C_ - 1);
    const int hh = threadIdx.x >> 7;
    const int j0 = hh * (H_ / 2);
    float acc = 0.f;
#pragma unroll 4
    for (int s = j0; s < j0 + H_ / 2; ++s) {
        int k = (s & ~31) + ((s & 31) >> 1) + ((s & 1) << 4);   // sigma(s)
        acc = fmaf((float)h[(size_t)b * H_ + s], W_ph[k * C_ + c], acc);
    }
    if (hh) part[c] = acc;
    __syncthreads();
    if (!hh) out[b * C_ + c] = acc + part[c] + b_p[c];
}

extern "C" void kernel_launch(void* const* d_in, const int* in_sizes, int n_in,
                              void* d_out, int out_size, void* d_ws, size_t ws_size,
                              hipStream_t stream) {
    const int*   x    = (const int*)d_in[0];
    const float* W_hx = (const float*)d_in[1];
    const float* W_hh = (const float*)d_in[2];
    const float* W_ph = (const float*)d_in[3];
    const float* b_h  = (const float*)d_in[4];
    const float* b_p  = (const float*)d_in[5];
    float* out = (float*)d_out;
    char* ws = (char*)d_ws;

    convert_whh<<<dim3(H_ / 64, H_ / 64), 256, 0, stream>>>(W_hh, (_Float16*)(ws + WS_BT));
    init_h<<<(B_ * H_) / 256, 256, 0, stream>>>(x, W_hx, b_h, ws);

    const int smem = 64 * BSTR2 * 2;   // 131840 B (fast path; fallback uses a prefix)
    (void)hipFuncSetAttribute((const void*)rnn_steps,
                              hipFuncAttributeMaxDynamicSharedMemorySize, smem);

    char* pws = ws;
    const int* px = x; const float* pwhx = W_hx; const float* pbh = b_h;
    void* args[] = {(void*)&pws, (void*)&px, (void*)&pwhx, (void*)&pbh};
    hipError_t e = hipLaunchCooperativeKernel((void*)rnn_steps, dim3(256), dim3(256),
                                              args, smem, stream);
    if (e != hipSuccess) {
        rnn_steps<<<dim3(256), dim3(256), smem, stream>>>(pws, px, pwhx, pbh);
    }

    final_proj<<<B_, 256, 0, stream>>>(ws, W_ph, b_p, out);
}

// Round 18
// 9449.716 us; speedup vs baseline: 1.2980x; 1.0201x over previous
//
#include <hip/hip_runtime.h>
#include <hip/hip_fp16.h>

#define B_ 256
#define T_ 512
#define H_ 2048
#define C_ 128
#define ASTR 520        // fallback LDS A stride (r12-proven)
#define BSTR2 1030      // fast-path LDS B stride (1024 used): ~2-way max bank aliasing (free)
#define POLLCAP 200000  // every cross-WG wait bounded -> bug = fast absmax-fail, never timeout

// ws byte offsets (10 MB, r12-proven capacity)
#define WS_H0 (0u)
#define WS_H1 (1u << 20)
#define WS_BT (2u << 20)   // 8 MB fp16 BT[n][s] (W_hh^T, sigma-permuted K)

typedef _Float16 half8 __attribute__((ext_vector_type(8)));
typedef float floatx4 __attribute__((ext_vector_type(4)));

// sync: [0..15] census; scnt[xcd]=g_sync[32+xcd*32]; fallback flags at g_sync+4384.
__device__ unsigned g_sync[8192];
__device__ _Float16 g_fb[2][8][32][H_];   // per-XCD h double buffer (XCD-local L2 resident)
// stream-order packed B-upper (K 1024..2048): [ns32][cp2][q8][bsel2][u4][lane64][8fp16] = 4 MB
__device__ _Float16 g_pk[2097152];

// sigma (r7-proven): within each 32-col block, storage 2j<-col j, 2j+1<-col j+16.
//   sigma(s) = (s&~31) + ((s&31)>>1) + ((s&1)<<4)

// IF$-coherent load (sc0 sc1) — fallback path (r7-proven).
__device__ __forceinline__ half8 llc_load16(const _Float16* p) {
    union { unsigned long long u[2]; half8 h; } v;
    const unsigned long long* q = (const unsigned long long*)p;
    v.u[0] = __hip_atomic_load(q,     __ATOMIC_RELAXED, __HIP_MEMORY_SCOPE_AGENT);
    v.u[1] = __hip_atomic_load(q + 1, __ATOMIC_RELAXED, __HIP_MEMORY_SCOPE_AGENT);
    return v.h;
}

__device__ __forceinline__ int xcc_id() {
    int x;
    asm volatile("s_getreg_b32 %0, hwreg(HW_REG_XCC_ID)" : "=s"(x));
    return x & 7;
}

// flags: AGENT-scope atomics (r7/r10/r11/r12/r17-proven).
__device__ __forceinline__ void flag_inc(unsigned* p) {
    __hip_atomic_fetch_add(p, 1u, __ATOMIC_RELAXED, __HIP_MEMORY_SCOPE_AGENT);
}
__device__ __forceinline__ void flag_poll_ge(const unsigned* p, unsigned tgt) {
    int n = 0;
    while (__hip_atomic_load(p, __ATOMIC_RELAXED, __HIP_MEMORY_SCOPE_AGENT) < tgt
           && n < POLLCAP) { __builtin_amdgcn_s_sleep(2); ++n; }
}

// ---- one-time: BT[n][s] = (fp16) W_hh[sigma(s)][n] ----
__global__ void convert_whh(const float* __restrict__ W, _Float16* __restrict__ BT) {
    __shared__ float tile[64][65];
    const int kb = blockIdx.x * 64, nb = blockIdx.y * 64;
    const int tid = threadIdx.x;
    const int rc = tid & 63, rr = tid >> 6;
#pragma unroll
    for (int i = 0; i < 16; ++i)
        tile[i * 4 + rr][rc] = W[(size_t)(kb + i * 4 + rr) * H_ + nb + rc];
    __syncthreads();
    const int j = tid & 15, blk = (tid >> 4) & 1, nof = tid >> 5;
#pragma unroll
    for (int i = 0; i < 8; ++i) {
        int n = i * 8 + nof;
        _Float16 v0 = (_Float16)tile[blk * 32 + j][n];
        _Float16 v1 = (_Float16)tile[blk * 32 + 16 + j][n];
        unsigned pk = ((unsigned)__builtin_bit_cast(unsigned short, v1) << 16)
                    |  (unsigned)__builtin_bit_cast(unsigned short, v0);
        *(unsigned*)(BT + (size_t)(nb + n) * H_ + kb + blk * 32 + 2 * j) = pk;
    }
}

// ---- one-time: stream-order pack of B-upper. idx -> (ns,cp,q,bsel,u,l); 8 fp16 each ----
__global__ void pack_bt(const _Float16* __restrict__ BT) {
    int idx = blockIdx.x * blockDim.x + threadIdx.x;   // 0..262143
    const int l    = idx & 63;
    const int u    = (idx >> 6) & 3;
    const int bsel = (idx >> 8) & 1;
    const int q    = (idx >> 9) & 7;
    const int cp   = (idx >> 12) & 1;
    const int ns   = idx >> 13;
    const int col  = 64 * ns + 32 * cp + 16 * bsel + (l & 15);
    const int kb   = 1024 + q * 128 + 8 * (l >> 4) + u * 32;
    *(half8*)(g_pk + (size_t)idx * 8) = *(const half8*)(BT + (size_t)col * H_ + kb);
}

// ---- h0 (permuted) = tanh(W_hx[x[:,0]] + b_h); zero all sync state ----
__global__ void init_h(const int* __restrict__ x, const float* __restrict__ W_hx,
                       const float* __restrict__ b_h, char* __restrict__ ws) {
    int idx = blockIdx.x * blockDim.x + threadIdx.x;
    if (idx < 8192) g_sync[idx] = 0;
    _Float16* h0 = (_Float16*)(ws + WS_H0);
    int b = idx >> 11, s = idx & (H_ - 1);
    int j = (s & ~31) + ((s & 31) >> 1) + ((s & 1) << 4);
    int xv = x[b * T_];
    h0[idx] = (_Float16)tanhf(W_hx[(size_t)xv * H_ + j] + b_h[j]);
}

// sc0 loads (L1-bypass, local-L2-hit) — r10/r17-proven instrument
#define AL(dst, blk) { const _Float16* _ab = ap + (blk) * 256;              \
    _Pragma("unroll") for (int u = 0; u < 8; ++u)                           \
        asm volatile("global_load_dwordx4 %0, %1, off offset:%2 sc0"        \
                     : "=v"(dst[u]) : "v"(_ab), "i"(u * 64)); }

// loop2 block: 4 A (sc0, strided L2-hit) + 8 packed-B (nt, lane-contiguous 1KB, sequential)
#define AL2(Aa, Bb0, Bb1, q) {                                              \
    const _Float16* _a2 = ap2 + (q) * 128;                                  \
    const _Float16* _p0 = pkp + (size_t)(q) * 4096;                         \
    const _Float16* _p1 = _p0 + 2048;                                       \
    _Pragma("unroll") for (int u = 0; u < 4; ++u)                           \
        asm volatile("global_load_dwordx4 %0, %1, off offset:%2 sc0"        \
                     : "=v"(Aa[u]) : "v"(_a2), "i"(u * 64));                \
    _Pragma("unroll") for (int u = 0; u < 4; ++u)                           \
        asm volatile("global_load_dwordx4 %0, %1, off offset:%2 nt"         \
                     : "=v"(Bb0[u]) : "v"(_p0), "i"(u * 1024));             \
    _Pragma("unroll") for (int u = 0; u < 4; ++u)                           \
        asm volatile("global_load_dwordx4 %0, %1, off offset:%2 nt"         \
                     : "=v"(Bb1[u]) : "v"(_p1), "i"(u * 1024)); }

#define VWAIT(n)                                                            \
    asm volatile("s_waitcnt vmcnt(" #n ")" ::: "memory");                   \
    __builtin_amdgcn_sched_barrier(0);

// fast path compute: B from LDS (loop1)
#define FC_LDS(src, blk)                                                    \
    _Pragma("unroll") for (int u = 0; u < 8; ++u) {                         \
        half8 b0v = *(const half8*)(bsp0 + ((blk) * 8 + u) * 32);           \
        half8 b1v = *(const half8*)(bsp1 + ((blk) * 8 + u) * 32);           \
        acc0 = __builtin_amdgcn_mfma_f32_16x16x32_f16(src[u], b0v, acc0, 0, 0, 0); \
        acc1 = __builtin_amdgcn_mfma_f32_16x16x32_f16(src[u], b1v, acc1, 0, 0, 0); \
    }

// fast path compute: B from registers (loop2)
#define FC_REG(Aa, Bb0, Bb1)                                                \
    _Pragma("unroll") for (int u = 0; u < 4; ++u) {                         \
        acc0 = __builtin_amdgcn_mfma_f32_16x16x32_f16(Aa[u], Bb0[u], acc0, 0, 0, 0); \
        acc1 = __builtin_amdgcn_mfma_f32_16x16x32_f16(Aa[u], Bb1[u], acc1, 0, 0, 0); \
    }

// fallback (r12-proven) pieces
#define POLLF(qq) {                                                         \
    int guard = 0;                                                          \
    for (;;) {                                                              \
        unsigned fvv = need;                                                \
        if (l < 4) fvv = __hip_atomic_load(&gflags[(rb * 16 + (qq) * 4 + l) * 4], \
                                           __ATOMIC_RELAXED, __HIP_MEMORY_SCOPE_AGENT); \
        if (__ballot(fvv >= need) == ~0ull) break;                          \
        if (++guard > POLLCAP) break;                                       \
        __builtin_amdgcn_s_sleep(2);                                        \
    } }

#define STAGE_LOAD(hb, qq, r) {                                             \
    const _Float16* sp = (hb) + (size_t)(rbr + srow) * H_ + (qq) * 512 + skb; \
    r[0] = llc_load16(sp);      r[1] = llc_load16(sp + 8);                  \
    r[2] = llc_load16(sp + 16); r[3] = llc_load16(sp + 24); }

#define STAGE_WRITE(buf, r) {                                               \
    _Float16* dp = Asl + (buf) * 16 * ASTR + srow * ASTR + skb;             \
    *(half8*)(dp)      = r[0]; *(half8*)(dp + 8)  = r[1];                   \
    *(half8*)(dp + 16) = r[2]; *(half8*)(dp + 24) = r[3]; }

#define COMPUTE(qq) {                                                       \
    const _Float16* ar  = Asl + ((qq) & 1) * 16 * ASTR + l15 * ASTR + kl;   \
    const _Float16* b0p = BT + (size_t)(cw + l15) * H_ + (qq) * 512 + kl;   \
    const _Float16* b1p = BT + (size_t)(cw + 16 + l15) * H_ + (qq) * 512 + kl; \
    _Pragma("unroll")                                                       \
    for (int i = 0; i < 16; ++i) {                                          \
        half8 a  = *(const half8*)(ar  + i * 32);                           \
        half8 b0 = *(const half8*)(b0p + i * 32);                           \
        half8 b1 = *(const half8*)(b1p + i * 32);                           \
        acc0 = __builtin_amdgcn_mfma_f32_16x16x32_f16(a, b0, acc0, 0, 0, 0);\
        acc1 = __builtin_amdgcn_mfma_f32_16x16x32_f16(a, b1, acc1, 0, 0, 0);\
    } }

// ---- recurrence: 256 WGs (1/CU) x 256 thr ----
// FAST (census: 32 WGs/XCD): XCD k owns rows [32k,32k+32); WG ns owns cols [64ns,64ns+64),
// full K (32x64=2048 ✓). h in XCD-local L2 (plain stores + sc0 loads); B = LDS K-lower +
// stream-order packed K-upper from g_pk (nt loads, L3-resident, no L2 thrash — replaces
// r17's 4KB-strided BT gather that was the 650 GB/s HBM wall). FALLBACK: r12 verbatim.
__global__ __launch_bounds__(256, 1)
void rnn_steps(char* __restrict__ ws, const int* __restrict__ x,
               const float* __restrict__ W_hx, const float* __restrict__ b_h) {
    extern __shared__ _Float16 lds[];
    __shared__ int s_fast, s_wslot;
    _Float16* h0 = (_Float16*)(ws + WS_H0);
    _Float16* h1 = (_Float16*)(ws + WS_H1);
    const _Float16* BT = (const _Float16*)(ws + WS_BT);
    unsigned* census = g_sync;
    unsigned* gflags = g_sync + 4384;

    const int bid = blockIdx.x;
    const int tid = threadIdx.x;
    const int myxcd = xcc_id();

    // census rendezvous (agent scope): wslot = arrival rank on this physical XCD
    if (tid == 0) {
        unsigned prev = __hip_atomic_fetch_add(&census[myxcd], 1u, __ATOMIC_RELAXED,
                                               __HIP_MEMORY_SCOPE_AGENT);
        __hip_atomic_fetch_add(&census[8], 1u, __ATOMIC_RELAXED, __HIP_MEMORY_SCOPE_AGENT);
        int p = 0;
        while (__hip_atomic_load(&census[8], __ATOMIC_RELAXED, __HIP_MEMORY_SCOPE_AGENT)
                   < 256u && p < POLLCAP) { __builtin_amdgcn_s_sleep(2); ++p; }
        int ok = (p < POLLCAP);
        if (ok)
            for (int i = 0; i < 8; ++i)
                if (__hip_atomic_load(&census[i], __ATOMIC_RELAXED, __HIP_MEMORY_SCOPE_AGENT)
                        != 32u) { ok = 0; break; }
        s_fast = ok; s_wslot = (int)prev;
    }
    __syncthreads();
    const bool fast = (s_fast != 0);
    const int wslot = s_wslot;

    const int w   = tid >> 6;
    const int l   = tid & 63;
    const int l15 = l & 15;
    const int kl  = (l >> 4) << 3;

    if (fast) {
        const int ns = wslot;              // 0..31: cols [64ns, 64ns+64), full K
        _Float16* bsf = lds;               // [64 cols][BSTR2] holding K 0..1024
        unsigned* scnt = &g_sync[32 + myxcd * 32];

        // LDS fill: B slice, K-lower-half (coalesced from BT)
        {
            const int c = tid >> 2, kseg = (tid & 3) * 256;
            const _Float16* src = BT + (size_t)(ns * 64 + c) * H_ + kseg;
            _Float16* dst = bsf + c * BSTR2 + kseg;
#pragma unroll
            for (int i = 0; i < 32; ++i)
                *(half8*)(dst + i * 8) = *(const half8*)(src + i * 8);
        }
        // prologue: WG ns copies local row ns of h0 into fb[0]
        {
            const _Float16* src = h0 + (size_t)(32 * myxcd + ns) * H_ + tid * 8;
            *(half8*)(&g_fb[0][myxcd][ns][tid * 8]) = *(const half8*)(src);
        }
        __syncthreads();
        if (tid == 0) flag_inc(scnt);      // prologue arrival (32 total)

        const int mrow = 16 * (w & 1);
        const int cpi  = w >> 1;           // col-pair 0/1 within the 64 cols
        const int cblk = 32 * cpi;
        const int arow = mrow + l15;
        const int r0l  = mrow + ((l >> 4) << 2);
        const int c0   = 64 * ns + cblk + l15;
        const float bh0 = b_h[c0], bh1 = b_h[c0 + 16];
        const _Float16* bsp0 = bsf + (cblk + l15) * BSTR2 + kl;
        const _Float16* bsp1 = bsf + (cblk + 16 + l15) * BSTR2 + kl;
        const _Float16* pkp  = g_pk + (size_t)(ns * 2 + cpi) * 32768 + l * 8;
        const unsigned uofs = (unsigned)(64 * ns + cblk) / 2 + (unsigned)l15;

        for (int t = 1; t < T_; ++t) {
            // gate: all 32 cohort WGs completed step t-1 (data ready + WAR-safe)
            if (tid == 0) flag_poll_ge(scnt, 32u * (unsigned)t);
            __syncthreads();

            int   xv[4];
            float wx0[4], wx1[4];
#pragma unroll
            for (int jj = 0; jj < 4; ++jj)
                xv[jj] = x[(32 * myxcd + r0l + jj) * T_ + t];
#pragma unroll
            for (int jj = 0; jj < 4; ++jj) {
                wx0[jj] = W_hx[(size_t)xv[jj] * H_ + c0];
                wx1[jj] = W_hx[(size_t)xv[jj] * H_ + c0 + 16];
            }
            asm volatile("" ::: "memory");

            const _Float16* ap  = &g_fb[(t - 1) & 1][myxcd][arow][kl];
            const _Float16* ap2 = ap + 1024;
            floatx4 acc0 = {0.f, 0.f, 0.f, 0.f}, acc1 = {0.f, 0.f, 0.f, 0.f};

            // loop1: K 0..1024, A sc0 pipeline, B from LDS
            half8 aA[8], aB[8];
            AL(aA, 0); AL(aB, 1);
            VWAIT(8);  FC_LDS(aA, 0);
            AL(aA, 2); VWAIT(8); FC_LDS(aB, 1);
            AL(aB, 3); VWAIT(8); FC_LDS(aA, 2);
            // loop2: K 1024..2048, 8 blocks of 128; A sc0 + packed-B nt (12 loads/blk)
            half8 a2A[4], b0A[4], b1A[4], a2B[4], b0B[4], b1B[4];
            AL2(a2A, b0A, b1A, 0);
            VWAIT(12); FC_LDS(aB, 3);
            AL2(a2B, b0B, b1B, 1); VWAIT(12); FC_REG(a2A, b0A, b1A);
            AL2(a2A, b0A, b1A, 2); VWAIT(12); FC_REG(a2B, b0B, b1B);
            AL2(a2B, b0B, b1B, 3); VWAIT(12); FC_REG(a2A, b0A, b1A);
            AL2(a2A, b0A, b1A, 4); VWAIT(12); FC_REG(a2B, b0B, b1B);
            AL2(a2B, b0B, b1B, 5); VWAIT(12); FC_REG(a2A, b0A, b1A);
            AL2(a2A, b0A, b1A, 6); VWAIT(12); FC_REG(a2B, b0B, b1B);
            AL2(a2B, b0B, b1B, 7); VWAIT(12); FC_REG(a2A, b0A, b1A);
            VWAIT(0);  FC_REG(a2B, b0B, b1B);

            // publish h(t): plain packed u32 stores -> dirty LOCAL L2 (sc0 readers hit it)
            _Float16* fbn = &g_fb[t & 1][myxcd][0][0];
#pragma unroll
            for (int jj = 0; jj < 4; ++jj) {
                float z0 = acc0[jj] + wx0[jj] + bh0;
                float z1 = acc1[jj] + wx1[jj] + bh1;
                _Float16 p0 = (_Float16)tanhf(z0), p1 = (_Float16)tanhf(z1);
                unsigned pv = ((unsigned)__builtin_bit_cast(unsigned short, p1) << 16)
                            |  (unsigned)__builtin_bit_cast(unsigned short, p0);
                ((unsigned*)(fbn + (size_t)(r0l + jj) * H_))[uofs] = pv;
                if (t == T_ - 1)
                    ((unsigned*)(h1 + (size_t)(32 * myxcd + r0l + jj) * H_))[uofs] = pv;
            }
            __syncthreads();               // vmcnt drain: stores acked at local L2
            if (tid == 0) flag_inc(scnt);  // arrive step t
        }
        return;
    }

    // ---------------- FALLBACK: r12-proven IF$ path (verbatim) ----------------
    _Float16* Asl = lds;                   // [2][16][ASTR]
    const int rb  = bid >> 4;
    const int cb  = bid & 15;
    const int nb  = cb * 128;
    const int cw  = nb + w * 32;
    const int rbr = rb * 16;
    const int srow = tid >> 4;
    const int skb  = (tid & 15) * 32;
    const int r0 = rbr + ((l >> 4) << 2);
    const int c0 = cw + l15;
    const float bh0 = b_h[c0], bh1 = b_h[c0 + 16];
    unsigned* myflag = &gflags[(rb * 16 + cb) * 4];

    for (int t = 1; t < T_; ++t) {
        const _Float16* __restrict__ hc = (t & 1) ? h0 : h1;
        _Float16* __restrict__ hn       = (t & 1) ? h1 : h0;
        const unsigned need = (unsigned)(t - 1);

        int   xv[4];
        float wx0[4], wx1[4];
#pragma unroll
        for (int jj = 0; jj < 4; ++jj) xv[jj] = x[(r0 + jj) * T_ + t];
#pragma unroll
        for (int jj = 0; jj < 4; ++jj) {
            wx0[jj] = W_hx[(size_t)xv[jj] * H_ + c0];
            wx1[jj] = W_hx[(size_t)xv[jj] * H_ + c0 + 16];
        }

        floatx4 acc0 = {0.f, 0.f, 0.f, 0.f}, acc1 = {0.f, 0.f, 0.f, 0.f};
        POLLF(0);
        {
            half8 rA[4];
            STAGE_LOAD(hc, 0, rA);
            STAGE_WRITE(0, rA);
        }
        __syncthreads();
#pragma unroll
        for (int q = 0; q < 4; ++q) {
            half8 rN[4];
            if (q < 3) { POLLF(q + 1); STAGE_LOAD(hc, q + 1, rN); }
            COMPUTE(q);
            if (q < 3) {
                __syncthreads();
                STAGE_WRITE((q + 1) & 1, rN);
                __syncthreads();
            }
        }
        unsigned o[4];
#pragma unroll
        for (int jj = 0; jj < 4; ++jj) {
            float z0 = acc0[jj] + wx0[jj] + bh0;
            float z1 = acc1[jj] + wx1[jj] + bh1;
            _Float16 p0 = (_Float16)tanhf(z0), p1 = (_Float16)tanhf(z1);
            unsigned pv = ((unsigned)__builtin_bit_cast(unsigned short, p1) << 16)
                        |  (unsigned)__builtin_bit_cast(unsigned short, p0);
            unsigned* dstp = (unsigned*)(hn + (size_t)(r0 + jj) * H_ + cw + 2 * l15);
            o[jj] = __hip_atomic_exchange(dstp, pv, __ATOMIC_RELAXED,
                                          __HIP_MEMORY_SCOPE_AGENT);
        }
        asm volatile("" :: "v"(o[0]), "v"(o[1]), "v"(o[2]), "v"(o[3]));
        __syncthreads();
        if (tid == 0) {
            __builtin_amdgcn_fence(__ATOMIC_RELEASE, "workgroup");
            __hip_atomic_fetch_add(myflag, 1u, __ATOMIC_RELAXED, __HIP_MEMORY_SCOPE_AGENT);
        }
    }
}

// ---- out[b,c] = h[b,:] @ W_ph + b_p (fp32); h in permuted storage order ----
__global__ void final_proj(const char* __restrict__ ws, const float* __restrict__ W_ph,
                           const float* __restrict__ b_p, float* __restrict__ out) {
    __shared__ float part[C_];
    const _Float16* h = (const _Float16*)(ws + WS_H1);   // h after t=511 (odd)
    const int b  = blockIdx.x;
    const int c  = threadIdx.x & (C_ - 1);
    const int hh = threadIdx.x >> 7;
    const int j0 = hh * (H_ / 2);
    float acc = 0.f;
#pragma unroll 4
    for (int s = j0; s < j0 + H_ / 2; ++s) {
        int k = (s & ~31) + ((s & 31) >> 1) + ((s & 1) << 4);   // sigma(s)
        acc = fmaf((float)h[(size_t)b * H_ + s], W_ph[k * C_ + c], acc);
    }
    if (hh) part[c] = acc;
    __syncthreads();
    if (!hh) out[b * C_ + c] = acc + part[c] + b_p[c];
}

extern "C" void kernel_launch(void* const* d_in, const int* in_sizes, int n_in,
                              void* d_out, int out_size, void* d_ws, size_t ws_size,
                              hipStream_t stream) {
    const int*   x    = (const int*)d_in[0];
    const float* W_hx = (const float*)d_in[1];
    const float* W_hh = (const float*)d_in[2];
    const float* W_ph = (const float*)d_in[3];
    const float* b_h  = (const float*)d_in[4];
    const float* b_p  = (const float*)d_in[5];
    float* out = (float*)d_out;
    char* ws = (char*)d_ws;

    convert_whh<<<dim3(H_ / 64, H_ / 64), 256, 0, stream>>>(W_hh, (_Float16*)(ws + WS_BT));
    pack_bt<<<1024, 256, 0, stream>>>((const _Float16*)(ws + WS_BT));
    init_h<<<(B_ * H_) / 256, 256, 0, stream>>>(x, W_hx, b_h, ws);

    const int smem = 64 * BSTR2 * 2;   // 131840 B (fast path; fallback uses a prefix)
    (void)hipFuncSetAttribute((const void*)rnn_steps,
                              hipFuncAttributeMaxDynamicSharedMemorySize, smem);

    char* pws = ws;
    const int* px = x; const float* pwhx = W_hx; const float* pbh = b_h;
    void* args[] = {(void*)&pws, (void*)&px, (void*)&pwhx, (void*)&pbh};
    hipError_t e = hipLaunchCooperativeKernel((void*)rnn_steps, dim3(256), dim3(256),
                                              args, smem, stream);
    if (e != hipSuccess) {
        rnn_steps<<<dim3(256), dim3(256), smem, stream>>>(pws, px, pwhx, pbh);
    }

    final_proj<<<B_, 256, 0, stream>>>(ws, W_ph, b_p, out);
}

// Round 19
// 8792.411 us; speedup vs baseline: 1.3951x; 1.0748x over previous
//
#include <hip/hip_runtime.h>
#include <hip/hip_fp16.h>

#define B_ 256
#define T_ 512
#define H_ 2048
#define C_ 128
#define ASTR 520        // fallback LDS A stride (r12-proven)
#define BSTR2 1030      // fast-path LDS B stride (1024 used): ~2-way max bank aliasing (free)
#define POLLCAP 200000  // every cross-WG wait bounded -> bug = fast absmax-fail, never timeout

// ws byte offsets (10 MB, r12-proven capacity)
#define WS_H0 (0u)
#define WS_H1 (1u << 20)
#define WS_BT (2u << 20)   // 8 MB fp16 BT[n][s] (W_hh^T, sigma-permuted K)

typedef _Float16 half8 __attribute__((ext_vector_type(8)));
typedef float floatx4 __attribute__((ext_vector_type(4)));

// sync: [0..15] census; scnt[xcd]=g_sync[32+xcd*32]; fallback flags at g_sync+4384.
__device__ unsigned g_sync[8192];
__device__ _Float16 g_fb[2][8][32][H_];   // per-XCD h double buffer (XCD-local L2 resident)
// stream-order packed B-upper (K 1024..2048): [ns32][w4][q8][u4][lane64][8fp16] = 4 MB
__device__ _Float16 g_pk[2097152];

// sigma (r7-proven): within each 32-col block, storage 2j<-col j, 2j+1<-col j+16.
//   sigma(s) = (s&~31) + ((s&31)>>1) + ((s&1)<<4)

// IF$-coherent load (sc0 sc1) — fallback path (r7-proven).
__device__ __forceinline__ half8 llc_load16(const _Float16* p) {
    union { unsigned long long u[2]; half8 h; } v;
    const unsigned long long* q = (const unsigned long long*)p;
    v.u[0] = __hip_atomic_load(q,     __ATOMIC_RELAXED, __HIP_MEMORY_SCOPE_AGENT);
    v.u[1] = __hip_atomic_load(q + 1, __ATOMIC_RELAXED, __HIP_MEMORY_SCOPE_AGENT);
    return v.h;
}

__device__ __forceinline__ int xcc_id() {
    int x;
    asm volatile("s_getreg_b32 %0, hwreg(HW_REG_XCC_ID)" : "=s"(x));
    return x & 7;
}

// flags: AGENT-scope atomics (r7/r10/r11/r12/r17-proven).
__device__ __forceinline__ void flag_inc(unsigned* p) {
    __hip_atomic_fetch_add(p, 1u, __ATOMIC_RELAXED, __HIP_MEMORY_SCOPE_AGENT);
}
__device__ __forceinline__ void flag_poll_ge(const unsigned* p, unsigned tgt) {
    int n = 0;
    while (__hip_atomic_load(p, __ATOMIC_RELAXED, __HIP_MEMORY_SCOPE_AGENT) < tgt
           && n < POLLCAP) { __builtin_amdgcn_s_sleep(2); ++n; }
}

// ---- one-time: BT[n][s] = (fp16) W_hh[sigma(s)][n] ----
__global__ void convert_whh(const float* __restrict__ W, _Float16* __restrict__ BT) {
    __shared__ float tile[64][65];
    const int kb = blockIdx.x * 64, nb = blockIdx.y * 64;
    const int tid = threadIdx.x;
    const int rc = tid & 63, rr = tid >> 6;
#pragma unroll
    for (int i = 0; i < 16; ++i)
        tile[i * 4 + rr][rc] = W[(size_t)(kb + i * 4 + rr) * H_ + nb + rc];
    __syncthreads();
    const int j = tid & 15, blk = (tid >> 4) & 1, nof = tid >> 5;
#pragma unroll
    for (int i = 0; i < 8; ++i) {
        int n = i * 8 + nof;
        _Float16 v0 = (_Float16)tile[blk * 32 + j][n];
        _Float16 v1 = (_Float16)tile[blk * 32 + 16 + j][n];
        unsigned pk = ((unsigned)__builtin_bit_cast(unsigned short, v1) << 16)
                    |  (unsigned)__builtin_bit_cast(unsigned short, v0);
        *(unsigned*)(BT + (size_t)(nb + n) * H_ + kb + blk * 32 + 2 * j) = pk;
    }
}

// ---- one-time: stream-order pack of B-upper for the (ns,w) wave decomposition ----
__global__ void pack_bt(const _Float16* __restrict__ BT) {
    int idx = blockIdx.x * blockDim.x + threadIdx.x;   // 0..262143
    const int l  = idx & 63;
    const int u  = (idx >> 6) & 3;
    const int q  = (idx >> 8) & 7;
    const int w  = (idx >> 11) & 3;
    const int ns = idx >> 13;
    const int col = 64 * ns + 16 * w + (l & 15);
    const int kb  = 1024 + q * 128 + u * 32 + 8 * (l >> 4);
    *(half8*)(g_pk + (size_t)idx * 8) = *(const half8*)(BT + (size_t)col * H_ + kb);
}

// ---- h0 (permuted) = tanh(W_hx[x[:,0]] + b_h); zero all sync state ----
__global__ void init_h(const int* __restrict__ x, const float* __restrict__ W_hx,
                       const float* __restrict__ b_h, char* __restrict__ ws) {
    int idx = blockIdx.x * blockDim.x + threadIdx.x;
    if (idx < 8192) g_sync[idx] = 0;
    _Float16* h0 = (_Float16*)(ws + WS_H0);
    int b = idx >> 11, s = idx & (H_ - 1);
    int j = (s & ~31) + ((s & 31) >> 1) + ((s & 1) << 4);
    int xv = x[b * T_];
    h0[idx] = (_Float16)tanhf(W_hx[(size_t)xv * H_ + j] + b_h[j]);
}

#define VWAIT(n)                                                            \
    asm volatile("s_waitcnt vmcnt(" #n ")" ::: "memory");                   \
    __builtin_amdgcn_sched_barrier(0);

// A-block load: rows l15 (L) and 16+l15 (H), K-block q (128 wide), sc0 (L2-fresh fb)
#define ALD(BL, BH, q) {                                                    \
    const _Float16* _aL = apL + (q) * 128;                                  \
    const _Float16* _aH = apH + (q) * 128;                                  \
    _Pragma("unroll") for (int u = 0; u < 4; ++u)                           \
        asm volatile("global_load_dwordx4 %0, %1, off offset:%2 sc0"        \
                     : "=v"(BL[u]) : "v"(_aL), "i"(u * 64));                \
    _Pragma("unroll") for (int u = 0; u < 4; ++u)                           \
        asm volatile("global_load_dwordx4 %0, %1, off offset:%2 sc0"        \
                     : "=v"(BH[u]) : "v"(_aH), "i"(u * 64)); }

// B-block load from packed stream (loop2-local block qp 0..7): PLAIN cached (L2/L3 retain)
#define BLD(BB, qp) {                                                       \
    const _Float16* _bp = pkp + (qp) * 2048;                                \
    _Pragma("unroll") for (int u = 0; u < 4; ++u)                           \
        asm volatile("global_load_dwordx4 %0, %1, off offset:%2"            \
                     : "=v"(BB[u]) : "v"(_bp), "i"(u * 1024)); }

// compute block q with B from LDS (loop1); one B-frag feeds both row-halves
#define CP_LDS(BL, BH, q)                                                   \
    _Pragma("unroll") for (int u = 0; u < 4; ++u) {                         \
        half8 bv = *(const half8*)(bsp + (q) * 128 + u * 32);               \
        acc0 = __builtin_amdgcn_mfma_f32_16x16x32_f16(BL[u], bv, acc0, 0, 0, 0); \
        acc1 = __builtin_amdgcn_mfma_f32_16x16x32_f16(BH[u], bv, acc1, 0, 0, 0); \
    }

// compute block with B from registers (loop2)
#define CP_REG(BL, BH, BB)                                                  \
    _Pragma("unroll") for (int u = 0; u < 4; ++u) {                         \
        acc0 = __builtin_amdgcn_mfma_f32_16x16x32_f16(BL[u], BB[u], acc0, 0, 0, 0); \
        acc1 = __builtin_amdgcn_mfma_f32_16x16x32_f16(BH[u], BB[u], acc1, 0, 0, 0); \
    }

// fallback (r12-proven) pieces
#define POLLF(qq) {                                                         \
    int guard = 0;                                                          \
    for (;;) {                                                              \
        unsigned fvv = need;                                                \
        if (l < 4) fvv = __hip_atomic_load(&gflags[(rb * 16 + (qq) * 4 + l) * 4], \
                                           __ATOMIC_RELAXED, __HIP_MEMORY_SCOPE_AGENT); \
        if (__ballot(fvv >= need) == ~0ull) break;                          \
        if (++guard > POLLCAP) break;                                       \
        __builtin_amdgcn_s_sleep(2);                                        \
    } }

#define STAGE_LOAD(hb, qq, r) {                                             \
    const _Float16* sp = (hb) + (size_t)(rbr + srow) * H_ + (qq) * 512 + skb; \
    r[0] = llc_load16(sp);      r[1] = llc_load16(sp + 8);                  \
    r[2] = llc_load16(sp + 16); r[3] = llc_load16(sp + 24); }

#define STAGE_WRITE(buf, r) {                                               \
    _Float16* dp = Asl + (buf) * 16 * ASTR + srow * ASTR + skb;             \
    *(half8*)(dp)      = r[0]; *(half8*)(dp + 8)  = r[1];                   \
    *(half8*)(dp + 16) = r[2]; *(half8*)(dp + 24) = r[3]; }

#define COMPUTE(qq) {                                                       \
    const _Float16* ar  = Asl + ((qq) & 1) * 16 * ASTR + l15 * ASTR + kl;   \
    const _Float16* b0p = BT + (size_t)(cw + l15) * H_ + (qq) * 512 + kl;   \
    const _Float16* b1p = BT + (size_t)(cw + 16 + l15) * H_ + (qq) * 512 + kl; \
    _Pragma("unroll")                                                       \
    for (int i = 0; i < 16; ++i) {                                          \
        half8 a  = *(const half8*)(ar  + i * 32);                           \
        half8 b0 = *(const half8*)(b0p + i * 32);                           \
        half8 b1 = *(const half8*)(b1p + i * 32);                           \
        acc0 = __builtin_amdgcn_mfma_f32_16x16x32_f16(a, b0, acc0, 0, 0, 0);\
        acc1 = __builtin_amdgcn_mfma_f32_16x16x32_f16(a, b1, acc1, 0, 0, 0);\
    } }

// ---- recurrence: 256 WGs (1/CU) x 256 thr ----
// FAST (census: 32 WGs/XCD): XCD k owns rows [32k,32k+32); WG ns owns cols [64ns,64ns+64).
// Wave w owns cols [16w,16w+16) x ALL 32 rows (acc0 rows 0-15, acc1 rows 16-31) -> B is
// UNIQUE per wave (r18 issued it 2x) and one B-frag feeds two MFMAs. B = LDS K-lower +
// packed K-upper stream, PLAIN cached loads (r18's nt blocked L3 retention -> 21 MB/step
// HBM; the 4 MB blob is shared by all XCDs -> L3-resident). Depth-2 counted-vmcnt
// pipeline over 16 uniform K-128 blocks. FALLBACK: r12 verbatim.
__global__ __launch_bounds__(256, 1)
void rnn_steps(char* __restrict__ ws, const int* __restrict__ x,
               const float* __restrict__ W_hx, const float* __restrict__ b_h) {
    extern __shared__ _Float16 lds[];
    __shared__ int s_fast, s_wslot;
    _Float16* h0 = (_Float16*)(ws + WS_H0);
    _Float16* h1 = (_Float16*)(ws + WS_H1);
    const _Float16* BT = (const _Float16*)(ws + WS_BT);
    unsigned* census = g_sync;
    unsigned* gflags = g_sync + 4384;

    const int bid = blockIdx.x;
    const int tid = threadIdx.x;
    const int myxcd = xcc_id();

    // census rendezvous (agent scope): wslot = arrival rank on this physical XCD
    if (tid == 0) {
        unsigned prev = __hip_atomic_fetch_add(&census[myxcd], 1u, __ATOMIC_RELAXED,
                                               __HIP_MEMORY_SCOPE_AGENT);
        __hip_atomic_fetch_add(&census[8], 1u, __ATOMIC_RELAXED, __HIP_MEMORY_SCOPE_AGENT);
        int p = 0;
        while (__hip_atomic_load(&census[8], __ATOMIC_RELAXED, __HIP_MEMORY_SCOPE_AGENT)
                   < 256u && p < POLLCAP) { __builtin_amdgcn_s_sleep(2); ++p; }
        int ok = (p < POLLCAP);
        if (ok)
            for (int i = 0; i < 8; ++i)
                if (__hip_atomic_load(&census[i], __ATOMIC_RELAXED, __HIP_MEMORY_SCOPE_AGENT)
                        != 32u) { ok = 0; break; }
        s_fast = ok; s_wslot = (int)prev;
    }
    __syncthreads();
    const bool fast = (s_fast != 0);
    const int wslot = s_wslot;

    const int w   = tid >> 6;
    const int l   = tid & 63;
    const int l15 = l & 15;
    const int kl  = (l >> 4) << 3;

    if (fast) {
        const int ns = wslot;              // 0..31: cols [64ns, 64ns+64), full K
        _Float16* bsf = lds;               // [64 cols][BSTR2] holding K 0..1024
        unsigned* scnt = &g_sync[32 + myxcd * 32];

        // LDS fill: B slice, K-lower-half (coalesced from BT)
        {
            const int c = tid >> 2, kseg = (tid & 3) * 256;
            const _Float16* src = BT + (size_t)(ns * 64 + c) * H_ + kseg;
            _Float16* dst = bsf + c * BSTR2 + kseg;
#pragma unroll
            for (int i = 0; i < 32; ++i)
                *(half8*)(dst + i * 8) = *(const half8*)(src + i * 8);
        }
        // prologue: WG ns copies local row ns of h0 into fb[0]
        {
            const _Float16* src = h0 + (size_t)(32 * myxcd + ns) * H_ + tid * 8;
            *(half8*)(&g_fb[0][myxcd][ns][tid * 8]) = *(const half8*)(src);
        }
        __syncthreads();
        if (tid == 0) flag_inc(scnt);      // prologue arrival (32 total)

        const int r0l = (l >> 4) << 2;     // C-frag row base (rows r0l.. and 16+r0l..)
        const int c0  = 64 * ns + 16 * w + l15;
        const float bh = b_h[c0];
        const _Float16* bsp = bsf + (16 * w + l15) * BSTR2 + kl;
        const _Float16* pkp = g_pk + (size_t)(ns * 4 + w) * 16384 + l * 8;
        const int blk32 = 2 * ns + (w >> 1);
        const int selem = blk32 * 32 + ((w & 1) ? (2 * l15 + 1) : (2 * l15));

        for (int t = 1; t < T_; ++t) {
            // gate: all 32 cohort WGs completed step t-1 (data ready + WAR-safe)
            if (tid == 0) flag_poll_ge(scnt, 32u * (unsigned)t);
            __syncthreads();

            int   xv[8];
            float wx[8];
#pragma unroll
            for (int jj = 0; jj < 4; ++jj) {
                xv[jj]     = x[(32 * myxcd + r0l + jj) * T_ + t];
                xv[4 + jj] = x[(32 * myxcd + 16 + r0l + jj) * T_ + t];
            }
#pragma unroll
            for (int jj = 0; jj < 8; ++jj)
                wx[jj] = W_hx[(size_t)xv[jj] * H_ + c0];
            asm volatile("" ::: "memory");

            const _Float16* fbp = &g_fb[(t - 1) & 1][myxcd][0][0];
            const _Float16* apL = fbp + (size_t)l15 * H_ + kl;
            const _Float16* apH = fbp + (size_t)(16 + l15) * H_ + kl;
            floatx4 acc0 = {0.f, 0.f, 0.f, 0.f}, acc1 = {0.f, 0.f, 0.f, 0.f};
            half8 XL[4], XH[4], YL[4], YH[4], ZL[4], ZH[4];
            half8 BXr[4], BYr[4], BZr[4];

            // 16 uniform K-128 blocks; depth-2 lookahead, counted vmcnt (traced by hand)
            ALD(XL, XH, 0); ALD(YL, YH, 1);
            VWAIT(8);  ALD(ZL, ZH, 2);             CP_LDS(XL, XH, 0);
            VWAIT(8);  ALD(XL, XH, 3);             CP_LDS(YL, YH, 1);
            VWAIT(8);  ALD(YL, YH, 4);             CP_LDS(ZL, ZH, 2);
            VWAIT(8);  ALD(ZL, ZH, 5);             CP_LDS(XL, XH, 3);
            VWAIT(8);  ALD(XL, XH, 6);             CP_LDS(YL, YH, 4);
            VWAIT(8);  ALD(YL, YH, 7);             CP_LDS(ZL, ZH, 5);
            VWAIT(8);  ALD(ZL, ZH, 8);  BLD(BZr, 0); CP_LDS(XL, XH, 6);
            VWAIT(8);  ALD(XL, XH, 9);  BLD(BXr, 1); CP_LDS(YL, YH, 7);
            VWAIT(12); ALD(YL, YH, 10); BLD(BYr, 2); CP_REG(ZL, ZH, BZr);
            VWAIT(12); ALD(ZL, ZH, 11); BLD(BZr, 3); CP_REG(XL, XH, BXr);
            VWAIT(12); ALD(XL, XH, 12); BLD(BXr, 4); CP_REG(YL, YH, BYr);
            VWAIT(12); ALD(YL, YH, 13); BLD(BYr, 5); CP_REG(ZL, ZH, BZr);
            VWAIT(12); ALD(ZL, ZH, 14); BLD(BZr, 6); CP_REG(XL, XH, BXr);
            VWAIT(12); ALD(XL, XH, 15); BLD(BXr, 7); CP_REG(YL, YH, BYr);
            VWAIT(12);                               CP_REG(ZL, ZH, BZr);
            VWAIT(0);                                CP_REG(XL, XH, BXr);

            // publish h(t): plain 2-byte stores (sigma storage) -> dirty LOCAL L2
            _Float16* fbn = &g_fb[t & 1][myxcd][0][0];
#pragma unroll
            for (int jj = 0; jj < 4; ++jj) {
                float zL = acc0[jj] + wx[jj]     + bh;
                float zH = acc1[jj] + wx[4 + jj] + bh;
                _Float16 pL = (_Float16)tanhf(zL);
                _Float16 pH = (_Float16)tanhf(zH);
                fbn[(size_t)(r0l + jj) * H_ + selem]      = pL;
                fbn[(size_t)(16 + r0l + jj) * H_ + selem] = pH;
                if (t == T_ - 1) {
                    h1[(size_t)(32 * myxcd + r0l + jj) * H_ + selem]      = pL;
                    h1[(size_t)(32 * myxcd + 16 + r0l + jj) * H_ + selem] = pH;
                }
            }
            __syncthreads();               // vmcnt drain: stores acked at local L2
            if (tid == 0) flag_inc(scnt);  // arrive step t
        }
        return;
    }

    // ---------------- FALLBACK: r12-proven IF$ path (verbatim) ----------------
    _Float16* Asl = lds;                   // [2][16][ASTR]
    const int rb  = bid >> 4;
    const int cb  = bid & 15;
    const int nb  = cb * 128;
    const int cw  = nb + w * 32;
    const int rbr = rb * 16;
    const int srow = tid >> 4;
    const int skb  = (tid & 15) * 32;
    const int r0 = rbr + ((l >> 4) << 2);
    const int c0 = cw + l15;
    const float bh0 = b_h[c0], bh1 = b_h[c0 + 16];
    unsigned* myflag = &gflags[(rb * 16 + cb) * 4];

    for (int t = 1; t < T_; ++t) {
        const _Float16* __restrict__ hc = (t & 1) ? h0 : h1;
        _Float16* __restrict__ hn       = (t & 1) ? h1 : h0;
        const unsigned need = (unsigned)(t - 1);

        int   xv[4];
        float wx0[4], wx1[4];
#pragma unroll
        for (int jj = 0; jj < 4; ++jj) xv[jj] = x[(r0 + jj) * T_ + t];
#pragma unroll
        for (int jj = 0; jj < 4; ++jj) {
            wx0[jj] = W_hx[(size_t)xv[jj] * H_ + c0];
            wx1[jj] = W_hx[(size_t)xv[jj] * H_ + c0 + 16];
        }

        floatx4 acc0 = {0.f, 0.f, 0.f, 0.f}, acc1 = {0.f, 0.f, 0.f, 0.f};
        POLLF(0);
        {
            half8 rA[4];
            STAGE_LOAD(hc, 0, rA);
            STAGE_WRITE(0, rA);
        }
        __syncthreads();
#pragma unroll
        for (int q = 0; q < 4; ++q) {
            half8 rN[4];
            if (q < 3) { POLLF(q + 1); STAGE_LOAD(hc, q + 1, rN); }
            COMPUTE(q);
            if (q < 3) {
                __syncthreads();
                STAGE_WRITE((q + 1) & 1, rN);
                __syncthreads();
            }
        }
        unsigned o[4];
#pragma unroll
        for (int jj = 0; jj < 4; ++jj) {
            float z0 = acc0[jj] + wx0[jj] + bh0;
            float z1 = acc1[jj] + wx1[jj] + bh1;
            _Float16 p0 = (_Float16)tanhf(z0), p1 = (_Float16)tanhf(z1);
            unsigned pv = ((unsigned)__builtin_bit_cast(unsigned short, p1) << 16)
                        |  (unsigned)__builtin_bit_cast(unsigned short, p0);
            unsigned* dstp = (unsigned*)(hn + (size_t)(r0 + jj) * H_ + cw + 2 * l15);
            o[jj] = __hip_atomic_exchange(dstp, pv, __ATOMIC_RELAXED,
                                          __HIP_MEMORY_SCOPE_AGENT);
        }
        asm volatile("" :: "v"(o[0]), "v"(o[1]), "v"(o[2]), "v"(o[3]));
        __syncthreads();
        if (tid == 0) {
            __builtin_amdgcn_fence(__ATOMIC_RELEASE, "workgroup");
            __hip_atomic_fetch_add(myflag, 1u, __ATOMIC_RELAXED, __HIP_MEMORY_SCOPE_AGENT);
        }
    }
}

// ---- out[b,c] = h[b,:] @ W_ph + b_p (fp32); h in permuted storage order ----
__global__ void final_proj(const char* __restrict__ ws, const float* __restrict__ W_ph,
                           const float* __restrict__ b_p, float* __restrict__ out) {
    __shared__ float part[C_];
    const _Float16* h = (const _Float16*)(ws + WS_H1);   // h after t=511 (odd)
    const int b  = blockIdx.x;
    const int c  = threadIdx.x & (C_ - 1);
    const int hh = threadIdx.x >> 7;
    const int j0 = hh * (H_ / 2);
    float acc = 0.f;
#pragma unroll 4
    for (int s = j0; s < j0 + H_ / 2; ++s) {
        int k = (s & ~31) + ((s & 31) >> 1) + ((s & 1) << 4);   // sigma(s)
        acc = fmaf((float)h[(size_t)b * H_ + s], W_ph[k * C_ + c], acc);
    }
    if (hh) part[c] = acc;
    __syncthreads();
    if (!hh) out[b * C_ + c] = acc + part[c] + b_p[c];
}

extern "C" void kernel_launch(void* const* d_in, const int* in_sizes, int n_in,
                              void* d_out, int out_size, void* d_ws, size_t ws_size,
                              hipStream_t stream) {
    const int*   x    = (const int*)d_in[0];
    const float* W_hx = (const float*)d_in[1];
    const float* W_hh = (const float*)d_in[2];
    const float* W_ph = (const float*)d_in[3];
    const float* b_h  = (const float*)d_in[4];
    const float* b_p  = (const float*)d_in[5];
    float* out = (float*)d_out;
    char* ws = (char*)d_ws;

    convert_whh<<<dim3(H_ / 64, H_ / 64), 256, 0, stream>>>(W_hh, (_Float16*)(ws + WS_BT));
    pack_bt<<<1024, 256, 0, stream>>>((const _Float16*)(ws + WS_BT));
    init_h<<<(B_ * H_) / 256, 256, 0, stream>>>(x, W_hx, b_h, ws);

    const int smem = 64 * BSTR2 * 2;   // 131840 B (fast path; fallback uses a prefix)
    (void)hipFuncSetAttribute((const void*)rnn_steps,
                              hipFuncAttributeMaxDynamicSharedMemorySize, smem);

    char* pws = ws;
    const int* px = x; const float* pwhx = W_hx; const float* pbh = b_h;
    void* args[] = {(void*)&pws, (void*)&px, (void*)&pwhx, (void*)&pbh};
    hipError_t e = hipLaunchCooperativeKernel((void*)rnn_steps, dim3(256), dim3(256),
                                              args, smem, stream);
    if (e != hipSuccess) {
        rnn_steps<<<dim3(256), dim3(256), smem, stream>>>(pws, px, pwhx, pbh);
    }

    final_proj<<<B_, 256, 0, stream>>>(ws, W_ph, b_p, out);
}

// Round 20
// 8128.189 us; speedup vs baseline: 1.5091x; 1.0817x over previous
//
#include <hip/hip_runtime.h>
#include <hip/hip_fp16.h>

#define B_ 256
#define T_ 512
#define H_ 2048
#define C_ 128
#define ASTR 520        // fallback LDS A stride (r12-proven)
#define BSTR2 1030      // fast-path LDS B stride: 515 dwords ≡ 3 mod 32 -> conflict-free
#define POLLCAP 200000  // every cross-WG wait bounded -> bug = fast absmax-fail, never timeout

// ws byte offsets (10 MB, r12-proven capacity)
#define WS_H0 (0u)
#define WS_H1 (1u << 20)
#define WS_BT (2u << 20)   // 8 MB fp16 BT[n][s] (W_hh^T, sigma-permuted K)

typedef _Float16 half8 __attribute__((ext_vector_type(8)));
typedef float floatx4 __attribute__((ext_vector_type(4)));

// sync: [0..15] census; scnt[xcd]=g_sync[32+xcd*32]; fallback flags at g_sync+4384.
__device__ unsigned g_sync[8192];
__device__ _Float16 g_fb[2][8][32][H_];   // per-XCD h double buffer (XCD-local L2 resident)
// stream-order packed B-upper (K 1024..2048): [ns32][w4][q8][u4][lane64][8fp16] = 4 MB
__device__ _Float16 g_pk[2097152];

// sigma (r7-proven): within each 32-col block, storage 2j<-col j, 2j+1<-col j+16.
//   sigma(s) = (s&~31) + ((s&31)>>1) + ((s&1)<<4)

// IF$-coherent load (sc0 sc1) — fallback path (r7-proven).
__device__ __forceinline__ half8 llc_load16(const _Float16* p) {
    union { unsigned long long u[2]; half8 h; } v;
    const unsigned long long* q = (const unsigned long long*)p;
    v.u[0] = __hip_atomic_load(q,     __ATOMIC_RELAXED, __HIP_MEMORY_SCOPE_AGENT);
    v.u[1] = __hip_atomic_load(q + 1, __ATOMIC_RELAXED, __HIP_MEMORY_SCOPE_AGENT);
    return v.h;
}

__device__ __forceinline__ int xcc_id() {
    int x;
    asm volatile("s_getreg_b32 %0, hwreg(HW_REG_XCC_ID)" : "=s"(x));
    return x & 7;
}

// flags: AGENT-scope atomics (r7/r10/r11/r12/r17-proven).
__device__ __forceinline__ void flag_inc(unsigned* p) {
    __hip_atomic_fetch_add(p, 1u, __ATOMIC_RELAXED, __HIP_MEMORY_SCOPE_AGENT);
}
__device__ __forceinline__ void flag_poll_ge(const unsigned* p, unsigned tgt) {
    int n = 0;
    while (__hip_atomic_load(p, __ATOMIC_RELAXED, __HIP_MEMORY_SCOPE_AGENT) < tgt
           && n < POLLCAP) { __builtin_amdgcn_s_sleep(2); ++n; }
}

// ---- one-time: BT[n][s] = (fp16) W_hh[sigma(s)][n] ----
__global__ void convert_whh(const float* __restrict__ W, _Float16* __restrict__ BT) {
    __shared__ float tile[64][65];
    const int kb = blockIdx.x * 64, nb = blockIdx.y * 64;
    const int tid = threadIdx.x;
    const int rc = tid & 63, rr = tid >> 6;
#pragma unroll
    for (int i = 0; i < 16; ++i)
        tile[i * 4 + rr][rc] = W[(size_t)(kb + i * 4 + rr) * H_ + nb + rc];
    __syncthreads();
    const int j = tid & 15, blk = (tid >> 4) & 1, nof = tid >> 5;
#pragma unroll
    for (int i = 0; i < 8; ++i) {
        int n = i * 8 + nof;
        _Float16 v0 = (_Float16)tile[blk * 32 + j][n];
        _Float16 v1 = (_Float16)tile[blk * 32 + 16 + j][n];
        unsigned pk = ((unsigned)__builtin_bit_cast(unsigned short, v1) << 16)
                    |  (unsigned)__builtin_bit_cast(unsigned short, v0);
        *(unsigned*)(BT + (size_t)(nb + n) * H_ + kb + blk * 32 + 2 * j) = pk;
    }
}

// ---- one-time: stream-order pack of B-upper for the (ns,w) wave decomposition ----
__global__ void pack_bt(const _Float16* __restrict__ BT) {
    int idx = blockIdx.x * blockDim.x + threadIdx.x;   // 0..262143
    const int l  = idx & 63;
    const int u  = (idx >> 6) & 3;
    const int q  = (idx >> 8) & 7;
    const int w  = (idx >> 11) & 3;
    const int ns = idx >> 13;
    const int col = 64 * ns + 16 * w + (l & 15);
    const int kb  = 1024 + q * 128 + u * 32 + 8 * (l >> 4);
    *(half8*)(g_pk + (size_t)idx * 8) = *(const half8*)(BT + (size_t)col * H_ + kb);
}

// ---- h0 (permuted) = tanh(W_hx[x[:,0]] + b_h); zero all sync state ----
__global__ void init_h(const int* __restrict__ x, const float* __restrict__ W_hx,
                       const float* __restrict__ b_h, char* __restrict__ ws) {
    int idx = blockIdx.x * blockDim.x + threadIdx.x;
    if (idx < 8192) g_sync[idx] = 0;
    _Float16* h0 = (_Float16*)(ws + WS_H0);
    int b = idx >> 11, s = idx & (H_ - 1);
    int j = (s & ~31) + ((s & 31) >> 1) + ((s & 1) << 4);
    int xv = x[b * T_];
    h0[idx] = (_Float16)tanhf(W_hx[(size_t)xv * H_ + j] + b_h[j]);
}

#define VWAIT(n)                                                            \
    asm volatile("s_waitcnt vmcnt(" #n ")" ::: "memory");                   \
    __builtin_amdgcn_sched_barrier(0);

// A-block load: rows l15 (L) and 16+l15 (H), K-block q (128 wide), sc0 (L2-fresh fb)
#define ALD(BL, BH, q) {                                                    \
    const _Float16* _aL = apL + (q) * 128;                                  \
    const _Float16* _aH = apH + (q) * 128;                                  \
    _Pragma("unroll") for (int u = 0; u < 4; ++u)                           \
        asm volatile("global_load_dwordx4 %0, %1, off offset:%2 sc0"        \
                     : "=v"(BL[u]) : "v"(_aL), "i"(u * 64));                \
    _Pragma("unroll") for (int u = 0; u < 4; ++u)                           \
        asm volatile("global_load_dwordx4 %0, %1, off offset:%2 sc0"        \
                     : "=v"(BH[u]) : "v"(_aH), "i"(u * 64)); }

// compute block q with B from LDS (K-lower); one B-frag feeds both row-halves
#define CP_LDS(BL, BH, q)                                                   \
    _Pragma("unroll") for (int u = 0; u < 4; ++u) {                         \
        half8 bv = *(const half8*)(bsp + (q) * 128 + u * 32);               \
        acc0 = __builtin_amdgcn_mfma_f32_16x16x32_f16(BL[u], bv, acc0, 0, 0, 0); \
        acc1 = __builtin_amdgcn_mfma_f32_16x16x32_f16(BH[u], bv, acc1, 0, 0, 0); \
    }

// compute block with B from persistent registers (K-upper block qp 0..7)
#define CP_BREG(BL, BH, qp)                                                 \
    _Pragma("unroll") for (int u = 0; u < 4; ++u) {                         \
        acc0 = __builtin_amdgcn_mfma_f32_16x16x32_f16(BL[u], breg[(qp) * 4 + u], acc0, 0, 0, 0); \
        acc1 = __builtin_amdgcn_mfma_f32_16x16x32_f16(BH[u], breg[(qp) * 4 + u], acc1, 0, 0, 0); \
    }

// fallback (r12-proven) pieces
#define POLLF(qq) {                                                         \
    int guard = 0;                                                          \
    for (;;) {                                                              \
        unsigned fvv = need;                                                \
        if (l < 4) fvv = __hip_atomic_load(&gflags[(rb * 16 + (qq) * 4 + l) * 4], \
                                           __ATOMIC_RELAXED, __HIP_MEMORY_SCOPE_AGENT); \
        if (__ballot(fvv >= need) == ~0ull) break;                          \
        if (++guard > POLLCAP) break;                                       \
        __builtin_amdgcn_s_sleep(2);                                        \
    } }

#define STAGE_LOAD(hb, qq, r) {                                             \
    const _Float16* sp = (hb) + (size_t)(rbr + srow) * H_ + (qq) * 512 + skb; \
    r[0] = llc_load16(sp);      r[1] = llc_load16(sp + 8);                  \
    r[2] = llc_load16(sp + 16); r[3] = llc_load16(sp + 24); }

#define STAGE_WRITE(buf, r) {                                               \
    _Float16* dp = Asl + (buf) * 16 * ASTR + srow * ASTR + skb;             \
    *(half8*)(dp)      = r[0]; *(half8*)(dp + 8)  = r[1];                   \
    *(half8*)(dp + 16) = r[2]; *(half8*)(dp + 24) = r[3]; }

#define COMPUTE(qq) {                                                       \
    const _Float16* ar  = Asl + ((qq) & 1) * 16 * ASTR + l15 * ASTR + kl;   \
    const _Float16* b0p = BT + (size_t)(cw + l15) * H_ + (qq) * 512 + kl;   \
    const _Float16* b1p = BT + (size_t)(cw + 16 + l15) * H_ + (qq) * 512 + kl; \
    _Pragma("unroll")                                                       \
    for (int i = 0; i < 16; ++i) {                                          \
        half8 a  = *(const half8*)(ar  + i * 32);                           \
        half8 b0 = *(const half8*)(b0p + i * 32);                           \
        half8 b1 = *(const half8*)(b1p + i * 32);                           \
        acc0 = __builtin_amdgcn_mfma_f32_16x16x32_f16(a, b0, acc0, 0, 0, 0);\
        acc1 = __builtin_amdgcn_mfma_f32_16x16x32_f16(a, b1, acc1, 0, 0, 0);\
    } }

// ---- recurrence: 256 WGs (1/CU) x 256 thr ----
// FAST (census: 32 WGs/XCD): XCD k owns rows [32k,32k+32); WG ns owns cols [64ns,64ns+64);
// wave w owns cols [16w,16w+16) x all 32 rows. B K-lower in LDS; B K-upper PERSISTENT IN
// VGPRS (half8 breg[32] = 128 VGPRs, loaded once — kills r19's 12 MB/step L2-miss B-stream
// that ran at 780 GB/s and set the step time). Loop traffic = A from XCD-local L2 only
// (sc0, counted-vmcnt depth-2 pipeline over 16 uniform K-128 blocks). FALLBACK: r12.
__global__ __launch_bounds__(256, 1)
void rnn_steps(char* __restrict__ ws, const int* __restrict__ x,
               const float* __restrict__ W_hx, const float* __restrict__ b_h) {
    extern __shared__ _Float16 lds[];
    __shared__ int s_fast, s_wslot;
    _Float16* h0 = (_Float16*)(ws + WS_H0);
    _Float16* h1 = (_Float16*)(ws + WS_H1);
    const _Float16* BT = (const _Float16*)(ws + WS_BT);
    unsigned* census = g_sync;
    unsigned* gflags = g_sync + 4384;

    const int bid = blockIdx.x;
    const int tid = threadIdx.x;
    const int myxcd = xcc_id();

    // census rendezvous (agent scope): wslot = arrival rank on this physical XCD
    if (tid == 0) {
        unsigned prev = __hip_atomic_fetch_add(&census[myxcd], 1u, __ATOMIC_RELAXED,
                                               __HIP_MEMORY_SCOPE_AGENT);
        __hip_atomic_fetch_add(&census[8], 1u, __ATOMIC_RELAXED, __HIP_MEMORY_SCOPE_AGENT);
        int p = 0;
        while (__hip_atomic_load(&census[8], __ATOMIC_RELAXED, __HIP_MEMORY_SCOPE_AGENT)
                   < 256u && p < POLLCAP) { __builtin_amdgcn_s_sleep(2); ++p; }
        int ok = (p < POLLCAP);
        if (ok)
            for (int i = 0; i < 8; ++i)
                if (__hip_atomic_load(&census[i], __ATOMIC_RELAXED, __HIP_MEMORY_SCOPE_AGENT)
                        != 32u) { ok = 0; break; }
        s_fast = ok; s_wslot = (int)prev;
    }
    __syncthreads();
    const bool fast = (s_fast != 0);
    const int wslot = s_wslot;

    const int w   = tid >> 6;
    const int l   = tid & 63;
    const int l15 = l & 15;
    const int kl  = (l >> 4) << 3;

    if (fast) {
        const int ns = wslot;              // 0..31: cols [64ns, 64ns+64), full K
        _Float16* bsf = lds;               // [64 cols][BSTR2] holding K 0..1024
        unsigned* scnt = &g_sync[32 + myxcd * 32];

        // LDS fill: B slice, K-lower-half (coalesced from BT)
        {
            const int c = tid >> 2, kseg = (tid & 3) * 256;
            const _Float16* src = BT + (size_t)(ns * 64 + c) * H_ + kseg;
            _Float16* dst = bsf + c * BSTR2 + kseg;
#pragma unroll
            for (int i = 0; i < 32; ++i)
                *(half8*)(dst + i * 8) = *(const half8*)(src + i * 8);
        }
        // prologue: WG ns copies local row ns of h0 into fb[0]
        {
            const _Float16* src = h0 + (size_t)(32 * myxcd + ns) * H_ + tid * 8;
            *(half8*)(&g_fb[0][myxcd][ns][tid * 8]) = *(const half8*)(src);
        }
        // prologue: load this wave's ENTIRE B-upper (16 cols x K 1024..2048) into VGPRs
        const _Float16* pkp = g_pk + (size_t)(ns * 4 + w) * 16384 + l * 8;
        half8 breg[32];
#pragma unroll
        for (int q = 0; q < 8; ++q)
#pragma unroll
            for (int u = 0; u < 4; ++u)
                breg[q * 4 + u] = *(const half8*)(pkp + q * 2048 + u * 512);
        __syncthreads();
        if (tid == 0) flag_inc(scnt);      // prologue arrival (32 total)

        const int r0l = (l >> 4) << 2;     // C-frag row base (rows r0l.. and 16+r0l..)
        const int c0  = 64 * ns + 16 * w + l15;
        const float bh = b_h[c0];
        const _Float16* bsp = bsf + (16 * w + l15) * BSTR2 + kl;
        const int blk32 = 2 * ns + (w >> 1);
        const int selem = blk32 * 32 + ((w & 1) ? (2 * l15 + 1) : (2 * l15));

        for (int t = 1; t < T_; ++t) {
            // gate: all 32 cohort WGs completed step t-1 (data ready + WAR-safe)
            if (tid == 0) flag_poll_ge(scnt, 32u * (unsigned)t);
            __syncthreads();

            int   xv[8];
            float wx[8];
#pragma unroll
            for (int jj = 0; jj < 4; ++jj) {
                xv[jj]     = x[(32 * myxcd + r0l + jj) * T_ + t];
                xv[4 + jj] = x[(32 * myxcd + 16 + r0l + jj) * T_ + t];
            }
#pragma unroll
            for (int jj = 0; jj < 8; ++jj)
                wx[jj] = W_hx[(size_t)xv[jj] * H_ + c0];
            asm volatile("" ::: "memory");

            const _Float16* fbp = &g_fb[(t - 1) & 1][myxcd][0][0];
            const _Float16* apL = fbp + (size_t)l15 * H_ + kl;
            const _Float16* apH = fbp + (size_t)(16 + l15) * H_ + kl;
            floatx4 acc0 = {0.f, 0.f, 0.f, 0.f}, acc1 = {0.f, 0.f, 0.f, 0.f};
            half8 XL[4], XH[4], YL[4], YH[4], ZL[4], ZH[4];

            // 16 uniform A-blocks (K-128 each); depth-2 lookahead, counted vmcnt.
            // Blocks 0-7: B from LDS. Blocks 8-15: B from breg (zero memory traffic).
            ALD(XL, XH, 0); ALD(YL, YH, 1);
            VWAIT(8);  ALD(ZL, ZH, 2);  CP_LDS(XL, XH, 0);
            VWAIT(8);  ALD(XL, XH, 3);  CP_LDS(YL, YH, 1);
            VWAIT(8);  ALD(YL, YH, 4);  CP_LDS(ZL, ZH, 2);
            VWAIT(8);  ALD(ZL, ZH, 5);  CP_LDS(XL, XH, 3);
            VWAIT(8);  ALD(XL, XH, 6);  CP_LDS(YL, YH, 4);
            VWAIT(8);  ALD(YL, YH, 7);  CP_LDS(ZL, ZH, 5);
            VWAIT(8);  ALD(ZL, ZH, 8);  CP_LDS(XL, XH, 6);
            VWAIT(8);  ALD(XL, XH, 9);  CP_LDS(YL, YH, 7);
            VWAIT(8);  ALD(YL, YH, 10); CP_BREG(ZL, ZH, 0);
            VWAIT(8);  ALD(ZL, ZH, 11); CP_BREG(XL, XH, 1);
            VWAIT(8);  ALD(XL, XH, 12); CP_BREG(YL, YH, 2);
            VWAIT(8);  ALD(YL, YH, 13); CP_BREG(ZL, ZH, 3);
            VWAIT(8);  ALD(ZL, ZH, 14); CP_BREG(XL, XH, 4);
            VWAIT(8);  ALD(XL, XH, 15); CP_BREG(YL, YH, 5);
            VWAIT(8);                   CP_BREG(ZL, ZH, 6);
            VWAIT(0);                   CP_BREG(XL, XH, 7);

            // publish h(t): plain 2-byte stores (sigma storage) -> dirty LOCAL L2
            _Float16* fbn = &g_fb[t & 1][myxcd][0][0];
#pragma unroll
            for (int jj = 0; jj < 4; ++jj) {
                float zL = acc0[jj] + wx[jj]     + bh;
                float zH = acc1[jj] + wx[4 + jj] + bh;
                _Float16 pL = (_Float16)tanhf(zL);
                _Float16 pH = (_Float16)tanhf(zH);
                fbn[(size_t)(r0l + jj) * H_ + selem]      = pL;
                fbn[(size_t)(16 + r0l + jj) * H_ + selem] = pH;
                if (t == T_ - 1) {
                    h1[(size_t)(32 * myxcd + r0l + jj) * H_ + selem]      = pL;
                    h1[(size_t)(32 * myxcd + 16 + r0l + jj) * H_ + selem] = pH;
                }
            }
            __syncthreads();               // vmcnt drain: stores acked at local L2
            if (tid == 0) flag_inc(scnt);  // arrive step t
        }
        return;
    }

    // ---------------- FALLBACK: r12-proven IF$ path (verbatim) ----------------
    _Float16* Asl = lds;                   // [2][16][ASTR]
    const int rb  = bid >> 4;
    const int cb  = bid & 15;
    const int nb  = cb * 128;
    const int cw  = nb + w * 32;
    const int rbr = rb * 16;
    const int srow = tid >> 4;
    const int skb  = (tid & 15) * 32;
    const int r0 = rbr + ((l >> 4) << 2);
    const int c0 = cw + l15;
    const float bh0 = b_h[c0], bh1 = b_h[c0 + 16];
    unsigned* myflag = &gflags[(rb * 16 + cb) * 4];

    for (int t = 1; t < T_; ++t) {
        const _Float16* __restrict__ hc = (t & 1) ? h0 : h1;
        _Float16* __restrict__ hn       = (t & 1) ? h1 : h0;
        const unsigned need = (unsigned)(t - 1);

        int   xv[4];
        float wx0[4], wx1[4];
#pragma unroll
        for (int jj = 0; jj < 4; ++jj) xv[jj] = x[(r0 + jj) * T_ + t];
#pragma unroll
        for (int jj = 0; jj < 4; ++jj) {
            wx0[jj] = W_hx[(size_t)xv[jj] * H_ + c0];
            wx1[jj] = W_hx[(size_t)xv[jj] * H_ + c0 + 16];
        }

        floatx4 acc0 = {0.f, 0.f, 0.f, 0.f}, acc1 = {0.f, 0.f, 0.f, 0.f};
        POLLF(0);
        {
            half8 rA[4];
            STAGE_LOAD(hc, 0, rA);
            STAGE_WRITE(0, rA);
        }
        __syncthreads();
#pragma unroll
        for (int q = 0; q < 4; ++q) {
            half8 rN[4];
            if (q < 3) { POLLF(q + 1); STAGE_LOAD(hc, q + 1, rN); }
            COMPUTE(q);
            if (q < 3) {
                __syncthreads();
                STAGE_WRITE((q + 1) & 1, rN);
                __syncthreads();
            }
        }
        unsigned o[4];
#pragma unroll
        for (int jj = 0; jj < 4; ++jj) {
            float z0 = acc0[jj] + wx0[jj] + bh0;
            float z1 = acc1[jj] + wx1[jj] + bh1;
            _Float16 p0 = (_Float16)tanhf(z0), p1 = (_Float16)tanhf(z1);
            unsigned pv = ((unsigned)__builtin_bit_cast(unsigned short, p1) << 16)
                        |  (unsigned)__builtin_bit_cast(unsigned short, p0);
            unsigned* dstp = (unsigned*)(hn + (size_t)(r0 + jj) * H_ + cw + 2 * l15);
            o[jj] = __hip_atomic_exchange(dstp, pv, __ATOMIC_RELAXED,
                                          __HIP_MEMORY_SCOPE_AGENT);
        }
        asm volatile("" :: "v"(o[0]), "v"(o[1]), "v"(o[2]), "v"(o[3]));
        __syncthreads();
        if (tid == 0) {
            __builtin_amdgcn_fence(__ATOMIC_RELEASE, "workgroup");
            __hip_atomic_fetch_add(myflag, 1u, __ATOMIC_RELAXED, __HIP_MEMORY_SCOPE_AGENT);
        }
    }
}

// ---- out[b,c] = h[b,:] @ W_ph + b_p (fp32); h in permuted storage order ----
__global__ void final_proj(const char* __restrict__ ws, const float* __restrict__ W_ph,
                           const float* __restrict__ b_p, float* __restrict__ out) {
    __shared__ float part[C_];
    const _Float16* h = (const _Float16*)(ws + WS_H1);   // h after t=511 (odd)
    const int b  = blockIdx.x;
    const int c  = threadIdx.x & (C_ - 1);
    const int hh = threadIdx.x >> 7;
    const int j0 = hh * (H_ / 2);
    float acc = 0.f;
#pragma unroll 4
    for (int s = j0; s < j0 + H_ / 2; ++s) {
        int k = (s & ~31) + ((s & 31) >> 1) + ((s & 1) << 4);   // sigma(s)
        acc = fmaf((float)h[(size_t)b * H_ + s], W_ph[k * C_ + c], acc);
    }
    if (hh) part[c] = acc;
    __syncthreads();
    if (!hh) out[b * C_ + c] = acc + part[c] + b_p[c];
}

extern "C" void kernel_launch(void* const* d_in, const int* in_sizes, int n_in,
                              void* d_out, int out_size, void* d_ws, size_t ws_size,
                              hipStream_t stream) {
    const int*   x    = (const int*)d_in[0];
    const float* W_hx = (const float*)d_in[1];
    const float* W_hh = (const float*)d_in[2];
    const float* W_ph = (const float*)d_in[3];
    const float* b_h  = (const float*)d_in[4];
    const float* b_p  = (const float*)d_in[5];
    float* out = (float*)d_out;
    char* ws = (char*)d_ws;

    convert_whh<<<dim3(H_ / 64, H_ / 64), 256, 0, stream>>>(W_hh, (_Float16*)(ws + WS_BT));
    pack_bt<<<1024, 256, 0, stream>>>((const _Float16*)(ws + WS_BT));
    init_h<<<(B_ * H_) / 256, 256, 0, stream>>>(x, W_hx, b_h, ws);

    const int smem = 64 * BSTR2 * 2;   // 131840 B (fast path; fallback uses a prefix)
    (void)hipFuncSetAttribute((const void*)rnn_steps,
                              hipFuncAttributeMaxDynamicSharedMemorySize, smem);

    char* pws = ws;
    const int* px = x; const float* pwhx = W_hx; const float* pbh = b_h;
    void* args[] = {(void*)&pws, (void*)&px, (void*)&pwhx, (void*)&pbh};
    hipError_t e = hipLaunchCooperativeKernel((void*)rnn_steps, dim3(256), dim3(256),
                                              args, smem, stream);
    if (e != hipSuccess) {
        rnn_steps<<<dim3(256), dim3(256), smem, stream>>>(pws, px, pwhx, pbh);
    }

    final_proj<<<B_, 256, 0, stream>>>(ws, W_ph, b_p, out);
}